// Round 16
// baseline (128.664 us; speedup 1.0000x reference)
//
#include <hip/hip_runtime.h>
#include <hip/hip_bf16.h>
#include <stdint.h>

// Problem constants (B,S,D,H,M) = (2,2048,1024,16,64), HD=64
#define B_  2
#define S_  2048
#define D_  1024
#define H_  16
#define HD_ 64
#define M_  64
#define SKM (S_ + M_)   // 2112
#define LOG2E 1.44269504088896340736f

typedef __attribute__((ext_vector_type(8))) short s16x8;
typedef __attribute__((ext_vector_type(4))) float f32x4;
typedef __attribute__((ext_vector_type(16))) float f32x16;

// global_load_lds width=16: linear LDS dest (base + lane*16), per-lane global src
#define GLOAD16(gp, lp) __builtin_amdgcn_global_load_lds( \
    (const __attribute__((address_space(1))) void*)(gp),  \
    (__attribute__((address_space(3))) void*)(lp), 16, 0, 0)

// counted vmcnt wait (T4): literal N, then pin scheduler (rule #18)
#define WAITVM(N) do { asm volatile("s_waitcnt vmcnt(" #N ")" ::: "memory"); \
                       __builtin_amdgcn_sched_barrier(0); } while (0)
// raw s_barrier WITHOUT the __syncthreads vmcnt(0) drain
#define BARRIER() do { asm volatile("" ::: "memory"); \
                       __builtin_amdgcn_s_barrier(); \
                       asm volatile("" ::: "memory"); } while (0)

__device__ __forceinline__ unsigned short f2bf(float f) {
  union { float f; unsigned int u; } v; v.f = f;
  unsigned int r = v.u + 0x7fffu + ((v.u >> 16) & 1u);  // RNE
  return (unsigned short)(r >> 16);
}

__device__ __forceinline__ unsigned pkbf(float lo, float hi) {
  union { __hip_bfloat162 b; unsigned u; } t;
  t.b = __float22bfloat162_rn(make_float2(lo, hi));   // -> v_cvt_pk_bf16_f32
  return t.u;
}

// ---- mask compaction: idx[b][j] = j-th unmasked key, cnt[b] = count ----------
__global__ void compact_mask(const int* __restrict__ mask,
                             int* __restrict__ idx, int* __restrict__ cnt) {
  const int b = blockIdx.x;
  __shared__ int base, wsum[4];
  if (threadIdx.x == 0) base = 0;
  const int lane = threadIdx.x & 63, w = threadIdx.x >> 6;
  __syncthreads();
  for (int c = 0; c < S_; c += 256) {
    int key = c + threadIdx.x;
    int mv = mask[b * S_ + key];
    unsigned long long bal = __ballot(mv != 0);
    int pre = __popcll(bal & ((1ull << lane) - 1ull));
    if (lane == 0) wsum[w] = __popcll(bal);
    __syncthreads();
    int woff = 0;
    for (int i = 0; i < w; i++) woff += wsum[i];
    int tot = wsum[0] + wsum[1] + wsum[2] + wsum[3];
    if (mv) idx[b * S_ + base + woff + pre] = key;
    __syncthreads();
    if (threadIdx.x == 0) base += tot;
    __syncthreads();
  }
  if (threadIdx.x == 0) cnt[b] = base;
}

// ---- ALL conversions in ONE launch: query + 4 weights + K/V gather -----------
__global__ void cvt_fused(const float* __restrict__ q,
                          const float* __restrict__ w0, const float* __restrict__ w1,
                          const float* __restrict__ w2, const float* __restrict__ w3,
                          const float* __restrict__ key, const float* __restrict__ value,
                          unsigned short* __restrict__ qf,
                          unsigned short* __restrict__ o0, unsigned short* __restrict__ o1,
                          unsigned short* __restrict__ o2, unsigned short* __restrict__ o3,
                          unsigned short* __restrict__ kf, unsigned short* __restrict__ vf,
                          const int* __restrict__ idx, const int* __restrict__ cnt) {
  const size_t NQs = (size_t)B_ * S_ * D_;
  if (blockIdx.x < 8192) {
    size_t i = ((size_t)blockIdx.x * 256 + threadIdx.x) * 4;
    const float* in; unsigned short* out; size_t off;
    if (i < NQs) { in = q; out = qf; off = i; }
    else {
      size_t j = i - NQs;
      int wsel = (int)(j >> 20);
      off = j & ((1u << 20) - 1);
      in  = (wsel == 0) ? w0 : (wsel == 1) ? w1 : (wsel == 2) ? w2 : w3;
      out = (wsel == 0) ? o0 : (wsel == 1) ? o1 : (wsel == 2) ? o2 : o3;
    }
    float4 v = *(const float4*)&in[off];
    ushort4 o;
    o.x = f2bf(v.x); o.y = f2bf(v.y); o.z = f2bf(v.z); o.w = f2bf(v.w);
    *(ushort4*)&out[off] = o;
  } else {
    int gid = blockIdx.x - 8192;         // [0, 8192)
    int kv = gid >> 12, rem = gid & 4095;
    int b = rem >> 11, j = rem & 2047;
    if (j >= cnt[b]) return;
    const float* in = kv ? value : key;
    unsigned short* out = kv ? vf : kf;
    int src = idx[b * S_ + j];
    const float* ip = in + ((size_t)(b * S_) + src) * D_;
    unsigned short* op = out + ((size_t)(b * S_) + j) * D_;
    int t = threadIdx.x * 4;
    float4 v = *(const float4*)&ip[t];
    ushort4 o;
    o.x = f2bf(v.x); o.y = f2bf(v.y); o.z = f2bf(v.z); o.w = f2bf(v.w);
    *(ushort4*)&op[t] = o;
  }
}

// --- merged Q/K/V projection + fused fill_mem (blocks 768..783) ---------------
// GEMM core = R12 (best measured): 128x128 tile, BK=32, 8 waves (64x32/wave),
// 2 buffers, TWO barriers per K-step, counted WAITVM(2) (T4: never drain in
// main loop). LDS 32 KB. K/V epilogue writes guarded to rows < cnt[b] so the
// fill_mem blocks are order-free within the same launch.
// Swizzle invariant (rule #21): LDS[r][c] = global[r][c ^ ((r>>1)&3)].
__global__ __launch_bounds__(512)
void gemm_qkv(const unsigned short* __restrict__ qf, const unsigned short* __restrict__ kf,
              const unsigned short* __restrict__ vf,
              const unsigned short* __restrict__ wq, const unsigned short* __restrict__ wk,
              const unsigned short* __restrict__ wv,
              const float* __restrict__ bq, const float* __restrict__ bk,
              const float* __restrict__ bv,
              const float* __restrict__ mk, const float* __restrict__ mv,
              unsigned short* __restrict__ Qb, unsigned short* __restrict__ Kb,
              unsigned short* __restrict__ Vt,
              const int* __restrict__ cnt) {
  __shared__ __align__(16) unsigned short As[2 * 128 * 32];
  __shared__ __align__(16) unsigned short Bs[2 * 128 * 32];

  // ---- fill_mem blocks: mem rows at key position cnt[b] (order-free) --------
  if (blockIdx.x >= 768) {
    int fb = blockIdx.x - 768;           // 0..15
#pragma unroll
    for (int k = 0; k < 8; k++) {
      int i = fb * 4096 + k * 512 + threadIdx.x;   // 0..65535
      int row = i >> 10, col = i & 1023;
      int hI = col >> 6, dd = col & 63;
      unsigned short kvv = f2bf(8.0f * mk[i]);
      unsigned short vvv = f2bf(8.0f * mv[i]);
#pragma unroll
      for (int b = 0; b < B_; b++) {
        int c = cnt[b];
        Kb[((size_t)(b * SKM) + c + row) * D_ + col] = kvv;
        Vt[((size_t)(b * H_ + hI) * HD_ + dd) * SKM + c + row] = vvv;
      }
    }
    return;
  }

  // T1: within each z-slice of 256 works, XCD (bid&7) owns 32 contiguous works
  const int z = blockIdx.x >> 8;
  const int local = blockIdx.x & 255;
  const int wsz = (local & 7) * 32 + (local >> 3);   // bijective (256 = 8*32)
  const int nBase = (wsz & 7) * 128, mBase = (wsz >> 3) * 128;
  const int bb = (mBase >= S_);
  const int climit = z ? cnt[bb] : S_;               // per-batch live-row limit
  if (z) {   // K/V: skip tiles entirely beyond the compacted row count
    if (mBase - bb * S_ >= climit) return;
  }
  const unsigned short* A  = (z == 0) ? qf : (z == 1) ? kf : vf;
  const unsigned short* Bw = (z == 0) ? wq : (z == 1) ? wk : wv;
  const float* bias        = (z == 0) ? bq : (z == 1) ? bk : bv;

  const int tid = threadIdx.x, lane = tid & 63;
  const int w = tid >> 6;                  // 0..7
  const int wr = w >> 2, wc = w & 3;       // 2x4 wave grid, 64x32 per wave
  const int lr = lane & 15, lk = lane >> 4;
  const int srow = tid >> 2;               // staging row 0..127
  const int cd = tid & 3;                  // dest chunk (linear)
  const int ca = cd ^ ((srow >> 1) & 3);   // inverse-swizzled source chunk
  const int NT = D_ / 32;                  // 32

  const f32x4 fz = {0.f, 0.f, 0.f, 0.f};
  f32x4 acc[4][2];
#pragma unroll
  for (int i = 0; i < 4; i++)
#pragma unroll
    for (int j = 0; j < 2; j++) acc[i][j] = fz;

#define STAGE_(buf, k0)                                                          \
  {                                                                              \
    GLOAD16(&A[(size_t)(mBase + srow) * D_ + (k0) + ca * 8],                     \
            &As[(buf) * (128 * 32) + (w * 16) * 32]);                            \
    GLOAD16(&Bw[(size_t)(nBase + srow) * D_ + (k0) + ca * 8],                    \
            &Bs[(buf) * (128 * 32) + (w * 16) * 32]);                            \
  }

  STAGE_(0, 0);                              // 2 loads in flight
  int cur = 0;
  for (int t = 0; t < NT; ++t) {
    if (t + 1 < NT) {
      STAGE_(cur ^ 1, (t + 1) * 32);         // 4 in flight
      WAITVM(2);                             // tile t's 2 done; t+1's in flight
    } else {
      WAITVM(0);
    }
    BARRIER();                               // all waves: tile t staged
    s16x8 af[4], bf[2];
#pragma unroll
    for (int mi = 0; mi < 4; mi++) {
      int row = wr * 64 + mi * 16 + lr;
      af[mi] = *(const s16x8*)&As[cur * (128 * 32) + row * 32 + ((lk ^ ((row >> 1) & 3)) << 3)];
    }
#pragma unroll
    for (int ni = 0; ni < 2; ni++) {
      int row = wc * 32 + ni * 16 + lr;
      bf[ni] = *(const s16x8*)&Bs[cur * (128 * 32) + row * 32 + ((lk ^ ((row >> 1) & 3)) << 3)];
    }
#pragma unroll
    for (int mi = 0; mi < 4; mi++)
#pragma unroll
      for (int ni = 0; ni < 2; ni++)
        acc[mi][ni] = __builtin_amdgcn_mfma_f32_16x16x32_bf16(af[mi], bf[ni], acc[mi][ni], 0, 0, 0);
    BARRIER();   // all waves' reads of buf[cur] latched -> safe to re-stage it
    cur ^= 1;
  }
#undef STAGE_

  const float alpha = (z == 0) ? 0.125f * LOG2E : 1.0f;   // Q: 1/sqrt(HD) * log2(e)
#pragma unroll
  for (int mi = 0; mi < 4; mi++)
#pragma unroll
    for (int ni = 0; ni < 2; ni++)
#pragma unroll
      for (int r = 0; r < 4; r++) {
        int gr = mBase + wr * 64 + mi * 16 + lk * 4 + r;
        int gc = nBase + wc * 32 + ni * 16 + lr;
        float v = (acc[mi][ni][r] + bias[gc]) * alpha;
        if (z == 2) {        // V^T: [b][h][d][key]; only live rows
          int s = gr - bb * S_;
          if (s < climit) {
            int hI = gc >> 6, dd = gc & 63;
            Vt[((size_t)(bb * H_ + hI) * HD_ + dd) * SKM + s] = f2bf(v);
          }
        } else if (z == 1) { // K rows with per-batch mem-row gap; only live rows
          int rr = gr - bb * S_;
          if (rr < climit) {
            int orow = gr + bb * M_;
            Kb[(size_t)orow * D_ + gc] = f2bf(v);
          }
        } else {
          Qb[(size_t)gr * D_ + gc] = f2bf(v);
        }
      }
}

// ---- output projection: f32 out, R12 core (2-buf, 2-barrier, WAITVM(2)) ------
__global__ __launch_bounds__(512)
void gemm_o(const unsigned short* __restrict__ A, const unsigned short* __restrict__ Bw,
            const float* __restrict__ bias, float* __restrict__ Cout) {
  __shared__ __align__(16) unsigned short As[2 * 128 * 32];
  __shared__ __align__(16) unsigned short Bs[2 * 128 * 32];
  const int local = blockIdx.x & 255;
  const int wsz = (local & 7) * 32 + (local >> 3);
  const int nBase = (wsz & 7) * 128, mBase = (wsz >> 3) * 128;
  const int tid = threadIdx.x, lane = tid & 63;
  const int w = tid >> 6;                  // 0..7
  const int wr = w >> 2, wc = w & 3;
  const int lr = lane & 15, lk = lane >> 4;
  const int srow = tid >> 2;
  const int cd = tid & 3;
  const int ca = cd ^ ((srow >> 1) & 3);
  const int NT = D_ / 32;

  const f32x4 fz = {0.f, 0.f, 0.f, 0.f};
  f32x4 acc[4][2];
#pragma unroll
  for (int i = 0; i < 4; i++)
#pragma unroll
    for (int j = 0; j < 2; j++) acc[i][j] = fz;

#define STAGE_(buf, k0)                                                          \
  {                                                                              \
    GLOAD16(&A[(size_t)(mBase + srow) * D_ + (k0) + ca * 8],                     \
            &As[(buf) * (128 * 32) + (w * 16) * 32]);                            \
    GLOAD16(&Bw[(size_t)(nBase + srow) * D_ + (k0) + ca * 8],                    \
            &Bs[(buf) * (128 * 32) + (w * 16) * 32]);                            \
  }

  STAGE_(0, 0);
  int cur = 0;
  for (int t = 0; t < NT; ++t) {
    if (t + 1 < NT) {
      STAGE_(cur ^ 1, (t + 1) * 32);
      WAITVM(2);
    } else {
      WAITVM(0);
    }
    BARRIER();
    s16x8 af[4], bf[2];
#pragma unroll
    for (int mi = 0; mi < 4; mi++) {
      int row = wr * 64 + mi * 16 + lr;
      af[mi] = *(const s16x8*)&As[cur * (128 * 32) + row * 32 + ((lk ^ ((row >> 1) & 3)) << 3)];
    }
#pragma unroll
    for (int ni = 0; ni < 2; ni++) {
      int row = wc * 32 + ni * 16 + lr;
      bf[ni] = *(const s16x8*)&Bs[cur * (128 * 32) + row * 32 + ((lk ^ ((row >> 1) & 3)) << 3)];
    }
#pragma unroll
    for (int mi = 0; mi < 4; mi++)
#pragma unroll
      for (int ni = 0; ni < 2; ni++)
        acc[mi][ni] = __builtin_amdgcn_mfma_f32_16x16x32_bf16(af[mi], bf[ni], acc[mi][ni], 0, 0, 0);
    BARRIER();
    cur ^= 1;
  }
#undef STAGE_

#pragma unroll
  for (int mi = 0; mi < 4; mi++)
#pragma unroll
    for (int ni = 0; ni < 2; ni++)
#pragma unroll
      for (int r = 0; r < 4; r++) {
        int gr = mBase + wr * 64 + mi * 16 + lk * 4 + r;
        int gc = nBase + wc * 32 + ni * 16 + lr;
        Cout[(size_t)gr * D_ + gc] = acc[mi][ni][r] + bias[gc];
      }
}

// -------- Flash attention: double-buffered K/V, ONE barrier per tile ----------
// (R15 version — the measured winner.) Block: 256 q-rows (8 waves x 32) for one
// (b,h). KV tile = 64 keys. T14 full form: LOAD(t+1) issued BEFORE compute;
// ds_write AFTER compute into buf^1 (no reader this iter); single barrier.
__global__ __launch_bounds__(512)
void attn_kernel(const unsigned short* __restrict__ Qb,
                 const unsigned short* __restrict__ Kb,
                 const unsigned short* __restrict__ VtG,
                 const int* __restrict__ cnt,
                 unsigned short* __restrict__ Xb) {
  __shared__ __align__(16) unsigned short Ks[2 * 64 * 64];   // [buf][key][d]
  __shared__ __align__(16) unsigned short Vs[2 * 64 * 64];   // [buf][d][key]

  const int tid = threadIdx.x, lane = tid & 63, w = tid >> 6;   // w: 0..7
  const int l31 = lane & 31, hh = lane >> 5;
  const int qt = blockIdx.x, h = blockIdx.y, b = blockIdx.z;

  const int total = cnt[b] + M_;            // live keys incl. memory slots
  const int nt = (total + 63) >> 6;         // tiles (<= 33)

  const int r0 = tid >> 3, c0 = tid & 7;          // staging: row 0..63, chunk 0..7
  const int ck = c0 ^ (r0 & 7);                   // swizzled chunk
  const unsigned short* Kg = Kb + (size_t)b * SKM * D_ + (size_t)h * HD_;
  const unsigned short* Vg = VtG + (size_t)(b * H_ + h) * HD_ * SKM;

  // Q fragments (B-operand of swapped QK^T): Q[q][ds*16 + hh*8 + i]
  const unsigned short* qp = Qb + ((size_t)(b * S_) + qt * 256 + w * 32 + l31) * D_ + h * HD_;
  s16x8 qf[4];
#pragma unroll
  for (int ds = 0; ds < 4; ds++) qf[ds] = *(const s16x8*)&qp[ds * 16 + hh * 8];

  f32x16 accO[2];
#pragma unroll
  for (int dt = 0; dt < 2; dt++)
#pragma unroll
    for (int j = 0; j < 16; j++) accO[dt][j] = 0.f;
  float m_r = -1e20f, l_r = 0.f;

  uint4 kr0, vr0;
  auto LOAD = [&](int kt) {   // rows < nt*64 <= 2112, always in-bounds
    kr0 = *(const uint4*)&Kg[(size_t)(kt * 64 + r0) * D_ + c0 * 8];
    vr0 = *(const uint4*)&Vg[(size_t)r0 * SKM + kt * 64 + c0 * 8];
  };

  LOAD(0);
  *(uint4*)&Ks[r0 * 64 + ck * 8] = kr0;
  *(uint4*)&Vs[r0 * 64 + ck * 8] = vr0;
  __syncthreads();
  int cur = 0;

  for (int kt = 0; kt < nt; ++kt) {
    const bool pre = (kt + 1 < nt);
    if (pre) LOAD(kt + 1);           // issue-early: lands during compute below

    // ---- S^T = K · Q^T : p0 = keys 0..31, p1 = keys 32..63 (lane: q=l31) ----
    const unsigned short* Kc = &Ks[cur * 4096];
    const unsigned short* Vc = &Vs[cur * 4096];
    f32x16 p0, p1;
#pragma unroll
    for (int j = 0; j < 16; j++) { p0[j] = 0.f; p1[j] = 0.f; }
    __builtin_amdgcn_s_setprio(1);
#pragma unroll
    for (int ds = 0; ds < 4; ds++) {
      s16x8 ka0 = *(const s16x8*)&Kc[l31 * 64 + (((ds * 2 + hh) ^ (l31 & 7)) << 3)];
      s16x8 ka1 = *(const s16x8*)&Kc[(32 + l31) * 64 + (((ds * 2 + hh) ^ (l31 & 7)) << 3)];
      p0 = __builtin_amdgcn_mfma_f32_32x32x16_bf16(ka0, qf[ds], p0, 0, 0, 0);
      p1 = __builtin_amdgcn_mfma_f32_32x32x16_bf16(ka1, qf[ds], p1, 0, 0, 0);
    }
    __builtin_amdgcn_s_setprio(0);

    // ---- tail tile: kill keys beyond `total` (key = (j&3)+8*(j>>2)+4*hh) ----
    if (kt == nt - 1) {
      int valid = total - kt * 64;   // 1..64
#pragma unroll
      for (int j = 0; j < 16; j++) {
        int kl = (j & 3) + 8 * (j >> 2) + 4 * hh;
        if (kl >= valid) p0[j] = -1e30f;
        if (kl + 32 >= valid) p1[j] = -1e30f;
      }
    }

    // ---- online softmax in log2 units, defer-max (T13, THR=8) ----
    float vmax = fmaxf(p0[0], p1[0]);
#pragma unroll
    for (int j = 1; j < 16; j++) vmax = fmaxf(vmax, fmaxf(p0[j], p1[j]));
    vmax = fmaxf(vmax, __shfl_xor(vmax, 32));
    if (!__all(vmax - m_r <= 8.0f)) {
      float mnew = fmaxf(m_r, vmax);
      float fac = __builtin_amdgcn_exp2f(m_r - mnew);
      m_r = mnew;
      l_r *= fac;
#pragma unroll
      for (int dt = 0; dt < 2; dt++)
#pragma unroll
        for (int j = 0; j < 16; j++) accO[dt][j] *= fac;
    }
    float sum = 0.f;
#pragma unroll
    for (int j = 0; j < 16; j++) {
      p0[j] = __builtin_amdgcn_exp2f(p0[j] - m_r); sum += p0[j];
      p1[j] = __builtin_amdgcn_exp2f(p1[j] - m_r); sum += p1[j];
    }
    sum += __shfl_xor(sum, 32);
    l_r += sum;

    // ---- build P^T fragments: frag[ks] = P[q][16ks + hh*8 + 0..7] as bf16x8 ----
    s16x8 pf_[4];
#pragma unroll
    for (int ks = 0; ks < 4; ks++) {
      const int base = (ks & 1) * 8;
#define ELT(t) ((ks >= 2) ? p1[base + (t)] : p0[base + (t)])
      unsigned w0 = pkbf(ELT(0), ELT(1));
      unsigned w1 = pkbf(ELT(2), ELT(3));
      unsigned w2 = pkbf(ELT(4), ELT(5));
      unsigned w3 = pkbf(ELT(6), ELT(7));
#undef ELT
      unsigned s0 = hh ? w0 : w2;         // h0 sends keys {8..11}, h1 sends {4..7}
      unsigned s1 = hh ? w1 : w3;
      unsigned g0 = (unsigned)__shfl_xor((int)s0, 32);
      unsigned g1 = (unsigned)__shfl_xor((int)s1, 32);
      union { s16x8 v; unsigned u[4]; } pf;
      pf.u[0] = hh ? g0 : w0;
      pf.u[1] = hh ? g1 : w1;
      pf.u[2] = hh ? w2 : g0;
      pf.u[3] = hh ? w3 : g1;
      pf_[ks] = pf.v;
    }

    // ---- O^T += V^T · P^T  (row d = dt*32+(j&3)+8*(j>>2)+4*hh, col q = l31) ----
    __builtin_amdgcn_s_setprio(1);
#pragma unroll
    for (int dt = 0; dt < 2; dt++)
#pragma unroll
      for (int ks = 0; ks < 4; ks++) {
        s16x8 va = *(const s16x8*)&Vc[(dt * 32 + l31) * 64 + (((ks * 2 + hh) ^ (l31 & 7)) << 3)];
        accO[dt] = __builtin_amdgcn_mfma_f32_32x32x16_bf16(va, pf_[ks], accO[dt], 0, 0, 0);
      }
    __builtin_amdgcn_s_setprio(0);

    // ---- write-late: stage tile kt+1 into buf^1 (no reader this iter) -------
    if (pre) {
      *(uint4*)&Ks[(cur ^ 1) * 4096 + r0 * 64 + ck * 8] = kr0;
      *(uint4*)&Vs[(cur ^ 1) * 4096 + r0 * 64 + ck * 8] = vr0;
      __syncthreads();               // ONE barrier per tile
      cur ^= 1;
    }
  }

  float invl = 1.0f / l_r;
  size_t orow = ((size_t)(b * S_) + qt * 256 + w * 32 + l31) * D_ + h * HD_;
#pragma unroll
  for (int dt = 0; dt < 2; dt++)
#pragma unroll
    for (int j = 0; j < 16; j++) {
      int d = dt * 32 + (j & 3) + 8 * (j >> 2) + 4 * hh;
      Xb[orow + d] = f2bf(accO[dt][j] * invl);
    }
}

// ------------------------------- launcher -------------------------------------
extern "C" void kernel_launch(void* const* d_in, const int* in_sizes, int n_in,
                              void* d_out, int out_size, void* d_ws, size_t ws_size,
                              hipStream_t stream) {
  const float* query = (const float*)d_in[0];
  const float* key   = (const float*)d_in[1];
  const float* value = (const float*)d_in[2];
  const int*   mask  = (const int*)d_in[3];
  const float* Wq    = (const float*)d_in[4];
  const float* bq    = (const float*)d_in[5];
  const float* Wk    = (const float*)d_in[6];
  const float* bk    = (const float*)d_in[7];
  const float* Wv    = (const float*)d_in[8];
  const float* bv    = (const float*)d_in[9];
  const float* Wo    = (const float*)d_in[10];
  const float* bo    = (const float*)d_in[11];
  const float* m_k   = (const float*)d_in[12];
  const float* m_v   = (const float*)d_in[13];

  const int NQ = B_ * S_ * D_;     // 4,194,304
  const int NW = D_ * D_;          // 1,048,576 = 2^20
  const int NK = B_ * SKM * D_;    // 4,325,376

  unsigned short* ws = (unsigned short*)d_ws;   // ~67.6 MB + 16 KB
  unsigned short* qf = ws;
  unsigned short* kf = qf + NQ;
  unsigned short* vf = kf + NQ;
  unsigned short* wq = vf + NQ;
  unsigned short* wk = wq + NW;
  unsigned short* wv = wk + NW;
  unsigned short* wo = wv + NW;
  unsigned short* Qb = wo + NW;
  unsigned short* Kb = Qb + NQ;
  unsigned short* Vt = Kb + NK;    // [b][h][d][key]
  unsigned short* Xb = Vt + NK;
  int* idx = (int*)(Xb + NQ);      // [B][S]
  int* cnt = idx + B_ * S_;        // [B]

  compact_mask<<<B_, 256, 0, stream>>>(mask, idx, cnt);
  // one launch: query+weights linear cvt (8192 blocks) + K/V gather (8192)
  cvt_fused<<<16384, 256, 0, stream>>>(query, Wq, Wk, Wv, Wo, key, value,
                                       qf, wq, wk, wv, wo, kf, vf, idx, cnt);

  // merged Q/K/V projection (768 blocks, R12 core) + fused fill_mem (16 blocks)
  gemm_qkv<<<784, 512, 0, stream>>>(qf, kf, vf, wq, wk, wv, bq, bk, bv,
                                    m_k, m_v, Qb, Kb, Vt, cnt);

  attn_kernel<<<dim3(S_ / 256, H_, B_), 512, 0, stream>>>(Qb, Kb, Vt, cnt, Xb);

  gemm_o<<<256, 512, 0, stream>>>(Xb, wo, bo, (float*)d_out);
}

// Round 17
// 125.477 us; speedup vs baseline: 1.0254x; 1.0254x over previous
//
#include <hip/hip_runtime.h>
#include <hip/hip_bf16.h>
#include <stdint.h>

// Problem constants (B,S,D,H,M) = (2,2048,1024,16,64), HD=64
#define B_  2
#define S_  2048
#define D_  1024
#define H_  16
#define HD_ 64
#define M_  64
#define SKM (S_ + M_)   // 2112
#define LOG2E 1.44269504088896340736f

typedef __attribute__((ext_vector_type(8))) short s16x8;
typedef __attribute__((ext_vector_type(4))) float f32x4;
typedef __attribute__((ext_vector_type(16))) float f32x16;

// global_load_lds width=16: linear LDS dest (base + lane*16), per-lane global src
#define GLOAD16(gp, lp) __builtin_amdgcn_global_load_lds( \
    (const __attribute__((address_space(1))) void*)(gp),  \
    (__attribute__((address_space(3))) void*)(lp), 16, 0, 0)

// counted vmcnt wait (T4): literal N, then pin scheduler (rule #18)
#define WAITVM(N) do { asm volatile("s_waitcnt vmcnt(" #N ")" ::: "memory"); \
                       __builtin_amdgcn_sched_barrier(0); } while (0)
// raw s_barrier WITHOUT the __syncthreads vmcnt(0) drain
#define BARRIER() do { asm volatile("" ::: "memory"); \
                       __builtin_amdgcn_s_barrier(); \
                       asm volatile("" ::: "memory"); } while (0)

__device__ __forceinline__ unsigned short f2bf(float f) {
  union { float f; unsigned int u; } v; v.f = f;
  unsigned int r = v.u + 0x7fffu + ((v.u >> 16) & 1u);  // RNE
  return (unsigned short)(r >> 16);
}

__device__ __forceinline__ unsigned pkbf(float lo, float hi) {
  union { __hip_bfloat162 b; unsigned u; } t;
  t.b = __float22bfloat162_rn(make_float2(lo, hi));   // -> v_cvt_pk_bf16_f32
  return t.u;
}

// ---- mask compaction: idx[b][j] = j-th unmasked key, cnt[b] = count ----------
__global__ void compact_mask(const int* __restrict__ mask,
                             int* __restrict__ idx, int* __restrict__ cnt) {
  const int b = blockIdx.x;
  __shared__ int base, wsum[4];
  if (threadIdx.x == 0) base = 0;
  const int lane = threadIdx.x & 63, w = threadIdx.x >> 6;
  __syncthreads();
  for (int c = 0; c < S_; c += 256) {
    int key = c + threadIdx.x;
    int mv = mask[b * S_ + key];
    unsigned long long bal = __ballot(mv != 0);
    int pre = __popcll(bal & ((1ull << lane) - 1ull));
    if (lane == 0) wsum[w] = __popcll(bal);
    __syncthreads();
    int woff = 0;
    for (int i = 0; i < w; i++) woff += wsum[i];
    int tot = wsum[0] + wsum[1] + wsum[2] + wsum[3];
    if (mv) idx[b * S_ + base + woff + pre] = key;
    __syncthreads();
    if (threadIdx.x == 0) base += tot;
    __syncthreads();
  }
  if (threadIdx.x == 0) cnt[b] = base;
}

// ---- ALL conversions in ONE launch: query + 4 weights + K/V gather -----------
__global__ void cvt_fused(const float* __restrict__ q,
                          const float* __restrict__ w0, const float* __restrict__ w1,
                          const float* __restrict__ w2, const float* __restrict__ w3,
                          const float* __restrict__ key, const float* __restrict__ value,
                          unsigned short* __restrict__ qf,
                          unsigned short* __restrict__ o0, unsigned short* __restrict__ o1,
                          unsigned short* __restrict__ o2, unsigned short* __restrict__ o3,
                          unsigned short* __restrict__ kf, unsigned short* __restrict__ vf,
                          const int* __restrict__ idx, const int* __restrict__ cnt) {
  const size_t NQs = (size_t)B_ * S_ * D_;
  if (blockIdx.x < 8192) {
    size_t i = ((size_t)blockIdx.x * 256 + threadIdx.x) * 4;
    const float* in; unsigned short* out; size_t off;
    if (i < NQs) { in = q; out = qf; off = i; }
    else {
      size_t j = i - NQs;
      int wsel = (int)(j >> 20);
      off = j & ((1u << 20) - 1);
      in  = (wsel == 0) ? w0 : (wsel == 1) ? w1 : (wsel == 2) ? w2 : w3;
      out = (wsel == 0) ? o0 : (wsel == 1) ? o1 : (wsel == 2) ? o2 : o3;
    }
    float4 v = *(const float4*)&in[off];
    ushort4 o;
    o.x = f2bf(v.x); o.y = f2bf(v.y); o.z = f2bf(v.z); o.w = f2bf(v.w);
    *(ushort4*)&out[off] = o;
  } else {
    int gid = blockIdx.x - 8192;         // [0, 8192)
    int kv = gid >> 12, rem = gid & 4095;
    int b = rem >> 11, j = rem & 2047;
    if (j >= cnt[b]) return;
    const float* in = kv ? value : key;
    unsigned short* out = kv ? vf : kf;
    int src = idx[b * S_ + j];
    const float* ip = in + ((size_t)(b * S_) + src) * D_;
    unsigned short* op = out + ((size_t)(b * S_) + j) * D_;
    int t = threadIdx.x * 4;
    float4 v = *(const float4*)&ip[t];
    ushort4 o;
    o.x = f2bf(v.x); o.y = f2bf(v.y); o.z = f2bf(v.z); o.w = f2bf(v.w);
    *(ushort4*)&op[t] = o;
  }
}

// ---- memory rows appended at key position cnt[b] (AFTER the K/V GEMMs) -------
__global__ void fill_mem(const float* __restrict__ mk, const float* __restrict__ mv,
                         unsigned short* __restrict__ Kb, unsigned short* __restrict__ VtG,
                         const int* __restrict__ cnt) {
  int i = blockIdx.x * 256 + threadIdx.x;     // 0 .. M_*D_-1
  int row = i >> 10, col = i & 1023;
  int hI = col >> 6, dd = col & 63;
  unsigned short kv = f2bf(8.0f * mk[i]);
  unsigned short vv = f2bf(8.0f * mv[i]);
#pragma unroll
  for (int b = 0; b < B_; b++) {
    int c = cnt[b];
    Kb[((size_t)(b * SKM) + c + row) * D_ + col] = kv;
    VtG[((size_t)(b * H_ + hI) * HD_ + dd) * SKM + c + row] = vv;
  }
}

// ------ GEMM: exact R12 core. 128x128 tile, BK=32, 8 waves (64x32/wave), ------
// 2 buffers, TWO barriers per K-step, counted WAITVM(2) (T4: never drain in
// main loop). LDS 32 KB. Swizzle (rule #21): LDS[r][c] = global[r][c^((r>>1)&3)].
__global__ __launch_bounds__(512)
void gemm_qkv(const unsigned short* __restrict__ qf, const unsigned short* __restrict__ kf,
              const unsigned short* __restrict__ vf,
              const unsigned short* __restrict__ wq, const unsigned short* __restrict__ wk,
              const unsigned short* __restrict__ wv,
              const float* __restrict__ bq, const float* __restrict__ bk,
              const float* __restrict__ bv,
              unsigned short* __restrict__ Qb, unsigned short* __restrict__ Kb,
              unsigned short* __restrict__ Vt,
              const int* __restrict__ cnt) {
  __shared__ __align__(16) unsigned short As[2 * 128 * 32];
  __shared__ __align__(16) unsigned short Bs[2 * 128 * 32];
  // T1: within each z-slice of 256 works, XCD (bid&7) owns 32 contiguous works
  const int z = blockIdx.x >> 8;
  const int local = blockIdx.x & 255;
  const int wsz = (local & 7) * 32 + (local >> 3);   // bijective (256 = 8*32)
  const int nBase = (wsz & 7) * 128, mBase = (wsz >> 3) * 128;
  const int bb = (mBase >= S_);
  if (z) {   // K/V: skip tiles entirely beyond the compacted row count
    if (mBase - bb * S_ >= cnt[bb]) return;
  }
  const unsigned short* A  = (z == 0) ? qf : (z == 1) ? kf : vf;
  const unsigned short* Bw = (z == 0) ? wq : (z == 1) ? wk : wv;
  const float* bias        = (z == 0) ? bq : (z == 1) ? bk : bv;

  const int tid = threadIdx.x, lane = tid & 63;
  const int w = tid >> 6;                  // 0..7
  const int wr = w >> 2, wc = w & 3;       // 2x4 wave grid, 64x32 per wave
  const int lr = lane & 15, lk = lane >> 4;
  const int srow = tid >> 2;               // staging row 0..127
  const int cd = tid & 3;                  // dest chunk (linear)
  const int ca = cd ^ ((srow >> 1) & 3);   // inverse-swizzled source chunk
  const int NT = D_ / 32;                  // 32

  const f32x4 fz = {0.f, 0.f, 0.f, 0.f};
  f32x4 acc[4][2];
#pragma unroll
  for (int i = 0; i < 4; i++)
#pragma unroll
    for (int j = 0; j < 2; j++) acc[i][j] = fz;

#define STAGE_(buf, k0)                                                          \
  {                                                                              \
    GLOAD16(&A[(size_t)(mBase + srow) * D_ + (k0) + ca * 8],                     \
            &As[(buf) * (128 * 32) + (w * 16) * 32]);                            \
    GLOAD16(&Bw[(size_t)(nBase + srow) * D_ + (k0) + ca * 8],                    \
            &Bs[(buf) * (128 * 32) + (w * 16) * 32]);                            \
  }

  STAGE_(0, 0);                              // 2 loads in flight
  int cur = 0;
  for (int t = 0; t < NT; ++t) {
    if (t + 1 < NT) {
      STAGE_(cur ^ 1, (t + 1) * 32);         // 4 in flight
      WAITVM(2);                             // tile t's 2 done; t+1's in flight
    } else {
      WAITVM(0);
    }
    BARRIER();                               // all waves: tile t staged
    s16x8 af[4], bf[2];
#pragma unroll
    for (int mi = 0; mi < 4; mi++) {
      int row = wr * 64 + mi * 16 + lr;
      af[mi] = *(const s16x8*)&As[cur * (128 * 32) + row * 32 + ((lk ^ ((row >> 1) & 3)) << 3)];
    }
#pragma unroll
    for (int ni = 0; ni < 2; ni++) {
      int row = wc * 32 + ni * 16 + lr;
      bf[ni] = *(const s16x8*)&Bs[cur * (128 * 32) + row * 32 + ((lk ^ ((row >> 1) & 3)) << 3)];
    }
#pragma unroll
    for (int mi = 0; mi < 4; mi++)
#pragma unroll
      for (int ni = 0; ni < 2; ni++)
        acc[mi][ni] = __builtin_amdgcn_mfma_f32_16x16x32_bf16(af[mi], bf[ni], acc[mi][ni], 0, 0, 0);
    BARRIER();   // all waves' reads of buf[cur] latched -> safe to re-stage it
    cur ^= 1;
  }
#undef STAGE_

  const float alpha = (z == 0) ? 0.125f * LOG2E : 1.0f;   // Q: 1/sqrt(HD) * log2(e)
#pragma unroll
  for (int mi = 0; mi < 4; mi++)
#pragma unroll
    for (int ni = 0; ni < 2; ni++)
#pragma unroll
      for (int r = 0; r < 4; r++) {
        int gr = mBase + wr * 64 + mi * 16 + lk * 4 + r;
        int gc = nBase + wc * 32 + ni * 16 + lr;
        float v = (acc[mi][ni][r] + bias[gc]) * alpha;
        if (z == 2) {        // V^T: [b][h][d][key]
          int s = gr - bb * S_;
          int hI = gc >> 6, dd = gc & 63;
          Vt[((size_t)(bb * H_ + hI) * HD_ + dd) * SKM + s] = f2bf(v);
        } else if (z == 1) { // K rows with per-batch mem-row gap
          int orow = gr + bb * M_;
          Kb[(size_t)orow * D_ + gc] = f2bf(v);
        } else {
          Qb[(size_t)gr * D_ + gc] = f2bf(v);
        }
      }
}

// ---- output projection: f32 out, R12 core (2-buf, 2-barrier, WAITVM(2)) ------
__global__ __launch_bounds__(512)
void gemm_o(const unsigned short* __restrict__ A, const unsigned short* __restrict__ Bw,
            const float* __restrict__ bias, float* __restrict__ Cout) {
  __shared__ __align__(16) unsigned short As[2 * 128 * 32];
  __shared__ __align__(16) unsigned short Bs[2 * 128 * 32];
  const int local = blockIdx.x & 255;
  const int wsz = (local & 7) * 32 + (local >> 3);
  const int nBase = (wsz & 7) * 128, mBase = (wsz >> 3) * 128;
  const int tid = threadIdx.x, lane = tid & 63;
  const int w = tid >> 6;                  // 0..7
  const int wr = w >> 2, wc = w & 3;
  const int lr = lane & 15, lk = lane >> 4;
  const int srow = tid >> 2;
  const int cd = tid & 3;
  const int ca = cd ^ ((srow >> 1) & 3);
  const int NT = D_ / 32;

  const f32x4 fz = {0.f, 0.f, 0.f, 0.f};
  f32x4 acc[4][2];
#pragma unroll
  for (int i = 0; i < 4; i++)
#pragma unroll
    for (int j = 0; j < 2; j++) acc[i][j] = fz;

#define STAGE_(buf, k0)                                                          \
  {                                                                              \
    GLOAD16(&A[(size_t)(mBase + srow) * D_ + (k0) + ca * 8],                     \
            &As[(buf) * (128 * 32) + (w * 16) * 32]);                            \
    GLOAD16(&Bw[(size_t)(nBase + srow) * D_ + (k0) + ca * 8],                    \
            &Bs[(buf) * (128 * 32) + (w * 16) * 32]);                            \
  }

  STAGE_(0, 0);
  int cur = 0;
  for (int t = 0; t < NT; ++t) {
    if (t + 1 < NT) {
      STAGE_(cur ^ 1, (t + 1) * 32);
      WAITVM(2);
    } else {
      WAITVM(0);
    }
    BARRIER();
    s16x8 af[4], bf[2];
#pragma unroll
    for (int mi = 0; mi < 4; mi++) {
      int row = wr * 64 + mi * 16 + lr;
      af[mi] = *(const s16x8*)&As[cur * (128 * 32) + row * 32 + ((lk ^ ((row >> 1) & 3)) << 3)];
    }
#pragma unroll
    for (int ni = 0; ni < 2; ni++) {
      int row = wc * 32 + ni * 16 + lr;
      bf[ni] = *(const s16x8*)&Bs[cur * (128 * 32) + row * 32 + ((lk ^ ((row >> 1) & 3)) << 3)];
    }
#pragma unroll
    for (int mi = 0; mi < 4; mi++)
#pragma unroll
      for (int ni = 0; ni < 2; ni++)
        acc[mi][ni] = __builtin_amdgcn_mfma_f32_16x16x32_bf16(af[mi], bf[ni], acc[mi][ni], 0, 0, 0);
    BARRIER();
    cur ^= 1;
  }
#undef STAGE_

#pragma unroll
  for (int mi = 0; mi < 4; mi++)
#pragma unroll
    for (int ni = 0; ni < 2; ni++)
#pragma unroll
      for (int r = 0; r < 4; r++) {
        int gr = mBase + wr * 64 + mi * 16 + lk * 4 + r;
        int gc = nBase + wc * 32 + ni * 16 + lr;
        Cout[(size_t)gr * D_ + gc] = acc[mi][ni][r] + bias[gc];
      }
}

// -------- Flash attention: double-buffered K/V, ONE barrier per tile ----------
// (R15/R16 version — measured winner.) Block: 256 q-rows (8 waves x 32) for one
// (b,h). KV tile = 64 keys. T14 full form: LOAD(t+1) issued BEFORE compute;
// ds_write AFTER compute into buf^1 (no reader this iter); single barrier.
__global__ __launch_bounds__(512)
void attn_kernel(const unsigned short* __restrict__ Qb,
                 const unsigned short* __restrict__ Kb,
                 const unsigned short* __restrict__ VtG,
                 const int* __restrict__ cnt,
                 unsigned short* __restrict__ Xb) {
  __shared__ __align__(16) unsigned short Ks[2 * 64 * 64];   // [buf][key][d]
  __shared__ __align__(16) unsigned short Vs[2 * 64 * 64];   // [buf][d][key]

  const int tid = threadIdx.x, lane = tid & 63, w = tid >> 6;   // w: 0..7
  const int l31 = lane & 31, hh = lane >> 5;
  const int qt = blockIdx.x, h = blockIdx.y, b = blockIdx.z;

  const int total = cnt[b] + M_;            // live keys incl. memory slots
  const int nt = (total + 63) >> 6;         // tiles (<= 33)

  const int r0 = tid >> 3, c0 = tid & 7;          // staging: row 0..63, chunk 0..7
  const int ck = c0 ^ (r0 & 7);                   // swizzled chunk
  const unsigned short* Kg = Kb + (size_t)b * SKM * D_ + (size_t)h * HD_;
  const unsigned short* Vg = VtG + (size_t)(b * H_ + h) * HD_ * SKM;

  // Q fragments (B-operand of swapped QK^T): Q[q][ds*16 + hh*8 + i]
  const unsigned short* qp = Qb + ((size_t)(b * S_) + qt * 256 + w * 32 + l31) * D_ + h * HD_;
  s16x8 qf[4];
#pragma unroll
  for (int ds = 0; ds < 4; ds++) qf[ds] = *(const s16x8*)&qp[ds * 16 + hh * 8];

  f32x16 accO[2];
#pragma unroll
  for (int dt = 0; dt < 2; dt++)
#pragma unroll
    for (int j = 0; j < 16; j++) accO[dt][j] = 0.f;
  float m_r = -1e20f, l_r = 0.f;

  uint4 kr0, vr0;
  auto LOAD = [&](int kt) {   // rows < nt*64 <= 2112, always in-bounds
    kr0 = *(const uint4*)&Kg[(size_t)(kt * 64 + r0) * D_ + c0 * 8];
    vr0 = *(const uint4*)&Vg[(size_t)r0 * SKM + kt * 64 + c0 * 8];
  };

  LOAD(0);
  *(uint4*)&Ks[r0 * 64 + ck * 8] = kr0;
  *(uint4*)&Vs[r0 * 64 + ck * 8] = vr0;
  __syncthreads();
  int cur = 0;

  for (int kt = 0; kt < nt; ++kt) {
    const bool pre = (kt + 1 < nt);
    if (pre) LOAD(kt + 1);           // issue-early: lands during compute below

    // ---- S^T = K · Q^T : p0 = keys 0..31, p1 = keys 32..63 (lane: q=l31) ----
    const unsigned short* Kc = &Ks[cur * 4096];
    const unsigned short* Vc = &Vs[cur * 4096];
    f32x16 p0, p1;
#pragma unroll
    for (int j = 0; j < 16; j++) { p0[j] = 0.f; p1[j] = 0.f; }
    __builtin_amdgcn_s_setprio(1);
#pragma unroll
    for (int ds = 0; ds < 4; ds++) {
      s16x8 ka0 = *(const s16x8*)&Kc[l31 * 64 + (((ds * 2 + hh) ^ (l31 & 7)) << 3)];
      s16x8 ka1 = *(const s16x8*)&Kc[(32 + l31) * 64 + (((ds * 2 + hh) ^ (l31 & 7)) << 3)];
      p0 = __builtin_amdgcn_mfma_f32_32x32x16_bf16(ka0, qf[ds], p0, 0, 0, 0);
      p1 = __builtin_amdgcn_mfma_f32_32x32x16_bf16(ka1, qf[ds], p1, 0, 0, 0);
    }
    __builtin_amdgcn_s_setprio(0);

    // ---- tail tile: kill keys beyond `total` (key = (j&3)+8*(j>>2)+4*hh) ----
    if (kt == nt - 1) {
      int valid = total - kt * 64;   // 1..64
#pragma unroll
      for (int j = 0; j < 16; j++) {
        int kl = (j & 3) + 8 * (j >> 2) + 4 * hh;
        if (kl >= valid) p0[j] = -1e30f;
        if (kl + 32 >= valid) p1[j] = -1e30f;
      }
    }

    // ---- online softmax in log2 units, defer-max (T13, THR=8) ----
    float vmax = fmaxf(p0[0], p1[0]);
#pragma unroll
    for (int j = 1; j < 16; j++) vmax = fmaxf(vmax, fmaxf(p0[j], p1[j]));
    vmax = fmaxf(vmax, __shfl_xor(vmax, 32));
    if (!__all(vmax - m_r <= 8.0f)) {
      float mnew = fmaxf(m_r, vmax);
      float fac = __builtin_amdgcn_exp2f(m_r - mnew);
      m_r = mnew;
      l_r *= fac;
#pragma unroll
      for (int dt = 0; dt < 2; dt++)
#pragma unroll
        for (int j = 0; j < 16; j++) accO[dt][j] *= fac;
    }
    float sum = 0.f;
#pragma unroll
    for (int j = 0; j < 16; j++) {
      p0[j] = __builtin_amdgcn_exp2f(p0[j] - m_r); sum += p0[j];
      p1[j] = __builtin_amdgcn_exp2f(p1[j] - m_r); sum += p1[j];
    }
    sum += __shfl_xor(sum, 32);
    l_r += sum;

    // ---- build P^T fragments: frag[ks] = P[q][16ks + hh*8 + 0..7] as bf16x8 ----
    s16x8 pf_[4];
#pragma unroll
    for (int ks = 0; ks < 4; ks++) {
      const int base = (ks & 1) * 8;
#define ELT(t) ((ks >= 2) ? p1[base + (t)] : p0[base + (t)])
      unsigned w0 = pkbf(ELT(0), ELT(1));
      unsigned w1 = pkbf(ELT(2), ELT(3));
      unsigned w2 = pkbf(ELT(4), ELT(5));
      unsigned w3 = pkbf(ELT(6), ELT(7));
#undef ELT
      unsigned s0 = hh ? w0 : w2;         // h0 sends keys {8..11}, h1 sends {4..7}
      unsigned s1 = hh ? w1 : w3;
      unsigned g0 = (unsigned)__shfl_xor((int)s0, 32);
      unsigned g1 = (unsigned)__shfl_xor((int)s1, 32);
      union { s16x8 v; unsigned u[4]; } pf;
      pf.u[0] = hh ? g0 : w0;
      pf.u[1] = hh ? g1 : w1;
      pf.u[2] = hh ? w2 : g0;
      pf.u[3] = hh ? w3 : g1;
      pf_[ks] = pf.v;
    }

    // ---- O^T += V^T · P^T  (row d = dt*32+(j&3)+8*(j>>2)+4*hh, col q = l31) ----
    __builtin_amdgcn_s_setprio(1);
#pragma unroll
    for (int dt = 0; dt < 2; dt++)
#pragma unroll
      for (int ks = 0; ks < 4; ks++) {
        s16x8 va = *(const s16x8*)&Vc[(dt * 32 + l31) * 64 + (((ks * 2 + hh) ^ (l31 & 7)) << 3)];
        accO[dt] = __builtin_amdgcn_mfma_f32_32x32x16_bf16(va, pf_[ks], accO[dt], 0, 0, 0);
      }
    __builtin_amdgcn_s_setprio(0);

    // ---- write-late: stage tile kt+1 into buf^1 (no reader this iter) -------
    if (pre) {
      *(uint4*)&Ks[(cur ^ 1) * 4096 + r0 * 64 + ck * 8] = kr0;
      *(uint4*)&Vs[(cur ^ 1) * 4096 + r0 * 64 + ck * 8] = vr0;
      __syncthreads();               // ONE barrier per tile
      cur ^= 1;
    }
  }

  float invl = 1.0f / l_r;
  size_t orow = ((size_t)(b * S_) + qt * 256 + w * 32 + l31) * D_ + h * HD_;
#pragma unroll
  for (int dt = 0; dt < 2; dt++)
#pragma unroll
    for (int j = 0; j < 16; j++) {
      int d = dt * 32 + (j & 3) + 8 * (j >> 2) + 4 * hh;
      Xb[orow + d] = f2bf(accO[dt][j] * invl);
    }
}

// ------------------------------- launcher -------------------------------------
extern "C" void kernel_launch(void* const* d_in, const int* in_sizes, int n_in,
                              void* d_out, int out_size, void* d_ws, size_t ws_size,
                              hipStream_t stream) {
  const float* query = (const float*)d_in[0];
  const float* key   = (const float*)d_in[1];
  const float* value = (const float*)d_in[2];
  const int*   mask  = (const int*)d_in[3];
  const float* Wq    = (const float*)d_in[4];
  const float* bq    = (const float*)d_in[5];
  const float* Wk    = (const float*)d_in[6];
  const float* bk    = (const float*)d_in[7];
  const float* Wv    = (const float*)d_in[8];
  const float* bv    = (const float*)d_in[9];
  const float* Wo    = (const float*)d_in[10];
  const float* bo    = (const float*)d_in[11];
  const float* m_k   = (const float*)d_in[12];
  const float* m_v   = (const float*)d_in[13];

  const int NQ = B_ * S_ * D_;     // 4,194,304
  const int NW = D_ * D_;          // 1,048,576 = 2^20
  const int NK = B_ * SKM * D_;    // 4,325,376

  unsigned short* ws = (unsigned short*)d_ws;   // ~67.6 MB + 16 KB
  unsigned short* qf = ws;
  unsigned short* kf = qf + NQ;
  unsigned short* vf = kf + NQ;
  unsigned short* wq = vf + NQ;
  unsigned short* wk = wq + NW;
  unsigned short* wv = wk + NW;
  unsigned short* wo = wv + NW;
  unsigned short* Qb = wo + NW;
  unsigned short* Kb = Qb + NQ;
  unsigned short* Vt = Kb + NK;    // [b][h][d][key]
  unsigned short* Xb = Vt + NK;
  int* idx = (int*)(Xb + NQ);      // [B][S]
  int* cnt = idx + B_ * S_;        // [B]

  compact_mask<<<B_, 256, 0, stream>>>(mask, idx, cnt);
  // one launch: query+weights linear cvt (8192 blocks) + K/V gather (8192)
  cvt_fused<<<16384, 256, 0, stream>>>(query, Wq, Wk, Wv, Wo, key, value,
                                       qf, wq, wk, wv, wo, kf, vf, idx, cnt);

  // merged Q/K/V projection — exact R12 kernel (best measured: 44.8 us)
  gemm_qkv<<<768, 512, 0, stream>>>(qf, kf, vf, wq, wk, wv, bq, bk, bv, Qb, Kb, Vt, cnt);
  // memory rows appended at key position cnt[b] — must run AFTER K/V GEMMs
  fill_mem<<<(M_ * D_) / 256, 256, 0, stream>>>(m_k, m_v, Kb, Vt, cnt);

  attn_kernel<<<dim3(S_ / 256, H_, B_), 512, 0, stream>>>(Qb, Kb, Vt, cnt, Xb);

  gemm_o<<<256, 512, 0, stream>>>(Xb, wo, bo, (float*)d_out);
}

// Round 18
// 122.869 us; speedup vs baseline: 1.0472x; 1.0212x over previous
//
#include <hip/hip_runtime.h>
#include <hip/hip_bf16.h>
#include <stdint.h>

// Problem constants (B,S,D,H,M) = (2,2048,1024,16,64), HD=64
#define B_  2
#define S_  2048
#define D_  1024
#define H_  16
#define HD_ 64
#define M_  64
#define SKM (S_ + M_)   // 2112
#define LOG2E 1.44269504088896340736f

typedef __attribute__((ext_vector_type(8))) short s16x8;
typedef __attribute__((ext_vector_type(4))) float f32x4;
typedef __attribute__((ext_vector_type(16))) float f32x16;

// global_load_lds width=16: linear LDS dest (base + lane*16), per-lane global src
#define GLOAD16(gp, lp) __builtin_amdgcn_global_load_lds( \
    (const __attribute__((address_space(1))) void*)(gp),  \
    (__attribute__((address_space(3))) void*)(lp), 16, 0, 0)

// counted vmcnt wait (T4): literal N, then pin scheduler (rule #18)
#define WAITVM(N) do { asm volatile("s_waitcnt vmcnt(" #N ")" ::: "memory"); \
                       __builtin_amdgcn_sched_barrier(0); } while (0)
// raw s_barrier WITHOUT the __syncthreads vmcnt(0) drain
#define BARRIER() do { asm volatile("" ::: "memory"); \
                       __builtin_amdgcn_s_barrier(); \
                       asm volatile("" ::: "memory"); } while (0)

__device__ __forceinline__ unsigned short f2bf(float f) {
  union { float f; unsigned int u; } v; v.f = f;
  unsigned int r = v.u + 0x7fffu + ((v.u >> 16) & 1u);  // RNE
  return (unsigned short)(r >> 16);
}

__device__ __forceinline__ unsigned pkbf(float lo, float hi) {
  union { __hip_bfloat162 b; unsigned u; } t;
  t.b = __float22bfloat162_rn(make_float2(lo, hi));   // -> v_cvt_pk_bf16_f32
  return t.u;
}

// ---- mask compaction: idx[b][j] = j-th unmasked key, cnt[b] = count ----------
__global__ void compact_mask(const int* __restrict__ mask,
                             int* __restrict__ idx, int* __restrict__ cnt) {
  const int b = blockIdx.x;
  __shared__ int base, wsum[4];
  if (threadIdx.x == 0) base = 0;
  const int lane = threadIdx.x & 63, w = threadIdx.x >> 6;
  __syncthreads();
  for (int c = 0; c < S_; c += 256) {
    int key = c + threadIdx.x;
    int mv = mask[b * S_ + key];
    unsigned long long bal = __ballot(mv != 0);
    int pre = __popcll(bal & ((1ull << lane) - 1ull));
    if (lane == 0) wsum[w] = __popcll(bal);
    __syncthreads();
    int woff = 0;
    for (int i = 0; i < w; i++) woff += wsum[i];
    int tot = wsum[0] + wsum[1] + wsum[2] + wsum[3];
    if (mv) idx[b * S_ + base + woff + pre] = key;
    __syncthreads();
    if (threadIdx.x == 0) base += tot;
    __syncthreads();
  }
  if (threadIdx.x == 0) cnt[b] = base;
}

// ---- ALL conversions in ONE launch: query + 4 weights + K/V gather -----------
__global__ void cvt_fused(const float* __restrict__ q,
                          const float* __restrict__ w0, const float* __restrict__ w1,
                          const float* __restrict__ w2, const float* __restrict__ w3,
                          const float* __restrict__ key, const float* __restrict__ value,
                          unsigned short* __restrict__ qf,
                          unsigned short* __restrict__ o0, unsigned short* __restrict__ o1,
                          unsigned short* __restrict__ o2, unsigned short* __restrict__ o3,
                          unsigned short* __restrict__ kf, unsigned short* __restrict__ vf,
                          const int* __restrict__ idx, const int* __restrict__ cnt) {
  const size_t NQs = (size_t)B_ * S_ * D_;
  if (blockIdx.x < 8192) {
    size_t i = ((size_t)blockIdx.x * 256 + threadIdx.x) * 4;
    const float* in; unsigned short* out; size_t off;
    if (i < NQs) { in = q; out = qf; off = i; }
    else {
      size_t j = i - NQs;
      int wsel = (int)(j >> 20);
      off = j & ((1u << 20) - 1);
      in  = (wsel == 0) ? w0 : (wsel == 1) ? w1 : (wsel == 2) ? w2 : w3;
      out = (wsel == 0) ? o0 : (wsel == 1) ? o1 : (wsel == 2) ? o2 : o3;
    }
    float4 v = *(const float4*)&in[off];
    ushort4 o;
    o.x = f2bf(v.x); o.y = f2bf(v.y); o.z = f2bf(v.z); o.w = f2bf(v.w);
    *(ushort4*)&out[off] = o;
  } else {
    int gid = blockIdx.x - 8192;         // [0, 8192)
    int kv = gid >> 12, rem = gid & 4095;
    int b = rem >> 11, j = rem & 2047;
    if (j >= cnt[b]) return;
    const float* in = kv ? value : key;
    unsigned short* out = kv ? vf : kf;
    int src = idx[b * S_ + j];
    const float* ip = in + ((size_t)(b * S_) + src) * D_;
    unsigned short* op = out + ((size_t)(b * S_) + j) * D_;
    int t = threadIdx.x * 4;
    float4 v = *(const float4*)&ip[t];
    ushort4 o;
    o.x = f2bf(v.x); o.y = f2bf(v.y); o.z = f2bf(v.z); o.w = f2bf(v.w);
    *(ushort4*)&op[t] = o;
  }
}

// ---- memory rows appended at key position cnt[b] (AFTER the K/V GEMMs) -------
__global__ void fill_mem(const float* __restrict__ mk, const float* __restrict__ mv,
                         unsigned short* __restrict__ Kb, unsigned short* __restrict__ VtG,
                         const int* __restrict__ cnt) {
  int i = blockIdx.x * 256 + threadIdx.x;     // 0 .. M_*D_-1
  int row = i >> 10, col = i & 1023;
  int hI = col >> 6, dd = col & 63;
  unsigned short kv = f2bf(8.0f * mk[i]);
  unsigned short vv = f2bf(8.0f * mv[i]);
#pragma unroll
  for (int b = 0; b < B_; b++) {
    int c = cnt[b];
    Kb[((size_t)(b * SKM) + c + row) * D_ + col] = kv;
    VtG[((size_t)(b * H_ + hI) * HD_ + dd) * SKM + c + row] = vv;
  }
}

// ------ GEMM: R12 geometry, BK=64. 128x128 tile, 8 waves (64x32/wave), --------
// 2 buffers, TWO barriers per K-step, counted WAITVM(4). Halves the number of
// K-steps (32->16) -> halves barrier convoys/waitcnt events at identical
// LDS-read:MFMA ratio. LDS 64 KB total -> still 2 blocks/CU.
// Swizzle (rule #21 both-sides, 8 chunks): LDS[r][c] = global[r][c ^ (r&7)].
// Staging: per wave gload dest = 1 KB = 8 rows of 64; thread (lane>>3) picks
// row-in-8, lane&7 picks dest chunk; src chunk = (lane&7) ^ (row&7).
__device__ __forceinline__ void gemm_core64(
    const unsigned short* __restrict__ A,
    const unsigned short* __restrict__ Bw,
    unsigned short* As, unsigned short* Bs,   // each 2*128*64 elems (32 KB)
    int mBase, int nBase,
    int tid, f32x4 acc[4][2]) {
  const int lane = tid & 63, w = tid >> 6;          // w: 0..7
  const int wr = w >> 2, wc = w & 3;                // wave grid 2x4 (64x32 each)
  const int lr = lane & 15, lk = lane >> 4;
  const int rg = lane >> 3;                         // row-in-8 (0..7)
  const int sr0 = w * 8 + rg;                       // staging rows sr0, sr0+64
  const int ca = (lane & 7) ^ (rg & 7);             // inverse-swizzled src chunk
  const int NT = D_ / 64;                           // 16

#define STAGE_(buf, k0)                                                          \
  {                                                                              \
    GLOAD16(&A[(size_t)(mBase + sr0) * D_ + (k0) + ca * 8],                      \
            &As[(buf) * (128 * 64) + (w * 8) * 64]);                             \
    GLOAD16(&A[(size_t)(mBase + 64 + sr0) * D_ + (k0) + ca * 8],                 \
            &As[(buf) * (128 * 64) + (64 + w * 8) * 64]);                        \
    GLOAD16(&Bw[(size_t)(nBase + sr0) * D_ + (k0) + ca * 8],                     \
            &Bs[(buf) * (128 * 64) + (w * 8) * 64]);                             \
    GLOAD16(&Bw[(size_t)(nBase + 64 + sr0) * D_ + (k0) + ca * 8],                \
            &Bs[(buf) * (128 * 64) + (64 + w * 8) * 64]);                        \
  }

  STAGE_(0, 0);                              // 4 loads in flight
  int cur = 0;
  for (int t = 0; t < NT; ++t) {
    if (t + 1 < NT) {
      STAGE_(cur ^ 1, (t + 1) * 64);         // 8 in flight
      WAITVM(4);                             // tile t's 4 done; t+1's in flight
    } else {
      WAITVM(0);
    }
    BARRIER();                               // all waves: tile t staged
#pragma unroll
    for (int ks = 0; ks < 2; ks++) {
      s16x8 af[4], bf[2];
#pragma unroll
      for (int mi = 0; mi < 4; mi++) {
        int row = wr * 64 + mi * 16 + lr;
        af[mi] = *(const s16x8*)&As[cur * (128 * 64) + row * 64 + (((ks * 4 + lk) ^ (row & 7)) << 3)];
      }
#pragma unroll
      for (int ni = 0; ni < 2; ni++) {
        int row = wc * 32 + ni * 16 + lr;
        bf[ni] = *(const s16x8*)&Bs[cur * (128 * 64) + row * 64 + (((ks * 4 + lk) ^ (row & 7)) << 3)];
      }
#pragma unroll
      for (int mi = 0; mi < 4; mi++)
#pragma unroll
        for (int ni = 0; ni < 2; ni++)
          acc[mi][ni] = __builtin_amdgcn_mfma_f32_16x16x32_bf16(af[mi], bf[ni], acc[mi][ni], 0, 0, 0);
    }
    BARRIER();   // all waves' reads of buf[cur] latched -> safe to re-stage it
    cur ^= 1;
  }
#undef STAGE_
}

// ---- merged Q/K/V projection, 1D grid 768, XCD-chunked work swizzle ----------
__global__ __launch_bounds__(512)
void gemm_qkv(const unsigned short* __restrict__ qf, const unsigned short* __restrict__ kf,
              const unsigned short* __restrict__ vf,
              const unsigned short* __restrict__ wq, const unsigned short* __restrict__ wk,
              const unsigned short* __restrict__ wv,
              const float* __restrict__ bq, const float* __restrict__ bk,
              const float* __restrict__ bv,
              unsigned short* __restrict__ Qb, unsigned short* __restrict__ Kb,
              unsigned short* __restrict__ Vt,
              const int* __restrict__ cnt) {
  __shared__ __align__(16) unsigned short As[2 * 128 * 64];
  __shared__ __align__(16) unsigned short Bs[2 * 128 * 64];
  // T1: within each z-slice of 256 works, XCD (bid&7) owns 32 contiguous works
  const int z = blockIdx.x >> 8;
  const int local = blockIdx.x & 255;
  const int wsz = (local & 7) * 32 + (local >> 3);   // bijective (256 = 8*32)
  const int nBase = (wsz & 7) * 128, mBase = (wsz >> 3) * 128;
  const int bb = (mBase >= S_);
  if (z) {   // K/V: skip tiles entirely beyond the compacted row count
    if (mBase - bb * S_ >= cnt[bb]) return;
  }
  const unsigned short* A  = (z == 0) ? qf : (z == 1) ? kf : vf;
  const unsigned short* Bw = (z == 0) ? wq : (z == 1) ? wk : wv;
  const float* bias        = (z == 0) ? bq : (z == 1) ? bk : bv;

  const int tid = threadIdx.x, lane = tid & 63;
  const int w = tid >> 6, wr = w >> 2, wc = w & 3;
  const int lr = lane & 15, lk = lane >> 4;

  const f32x4 fz = {0.f, 0.f, 0.f, 0.f};
  f32x4 acc[4][2];
#pragma unroll
  for (int i = 0; i < 4; i++)
#pragma unroll
    for (int j = 0; j < 2; j++) acc[i][j] = fz;

  gemm_core64(A, Bw, As, Bs, mBase, nBase, tid, acc);

  const float alpha = (z == 0) ? 0.125f * LOG2E : 1.0f;   // Q: 1/sqrt(HD) * log2(e)
#pragma unroll
  for (int mi = 0; mi < 4; mi++)
#pragma unroll
    for (int ni = 0; ni < 2; ni++)
#pragma unroll
      for (int r = 0; r < 4; r++) {
        int gr = mBase + wr * 64 + mi * 16 + lk * 4 + r;
        int gc = nBase + wc * 32 + ni * 16 + lr;
        float v = (acc[mi][ni][r] + bias[gc]) * alpha;
        if (z == 2) {        // V^T: [b][h][d][key]
          int s = gr - bb * S_;
          int hI = gc >> 6, dd = gc & 63;
          Vt[((size_t)(bb * H_ + hI) * HD_ + dd) * SKM + s] = f2bf(v);
        } else if (z == 1) { // K rows with per-batch mem-row gap
          int orow = gr + bb * M_;
          Kb[(size_t)orow * D_ + gc] = f2bf(v);
        } else {
          Qb[(size_t)gr * D_ + gc] = f2bf(v);
        }
      }
}

// ---- output projection: f32 out, BK=64 core ----------------------------------
__global__ __launch_bounds__(512)
void gemm_o(const unsigned short* __restrict__ A, const unsigned short* __restrict__ Bw,
            const float* __restrict__ bias, float* __restrict__ Cout) {
  __shared__ __align__(16) unsigned short As[2 * 128 * 64];
  __shared__ __align__(16) unsigned short Bs[2 * 128 * 64];
  const int local = blockIdx.x & 255;
  const int wsz = (local & 7) * 32 + (local >> 3);
  const int nBase = (wsz & 7) * 128, mBase = (wsz >> 3) * 128;
  const int tid = threadIdx.x, lane = tid & 63;
  const int w = tid >> 6, wr = w >> 2, wc = w & 3;
  const int lr = lane & 15, lk = lane >> 4;

  const f32x4 fz = {0.f, 0.f, 0.f, 0.f};
  f32x4 acc[4][2];
#pragma unroll
  for (int i = 0; i < 4; i++)
#pragma unroll
    for (int j = 0; j < 2; j++) acc[i][j] = fz;

  gemm_core64(A, Bw, As, Bs, mBase, nBase, tid, acc);

#pragma unroll
  for (int mi = 0; mi < 4; mi++)
#pragma unroll
    for (int ni = 0; ni < 2; ni++)
#pragma unroll
      for (int r = 0; r < 4; r++) {
        int gr = mBase + wr * 64 + mi * 16 + lk * 4 + r;
        int gc = nBase + wc * 32 + ni * 16 + lr;
        Cout[(size_t)gr * D_ + gc] = acc[mi][ni][r] + bias[gc];
      }
}

// -------- Flash attention: double-buffered K/V, ONE barrier per tile ----------
// Block: 256 q-rows (8 waves x 32) for one (b,h). KV tile = 64 keys.
// T14 full form: LOAD(t+1) issued BEFORE compute; ds_write AFTER compute into
// buf^1 (no reader this iter); single barrier per tile.
__global__ __launch_bounds__(512)
void attn_kernel(const unsigned short* __restrict__ Qb,
                 const unsigned short* __restrict__ Kb,
                 const unsigned short* __restrict__ VtG,
                 const int* __restrict__ cnt,
                 unsigned short* __restrict__ Xb) {
  __shared__ __align__(16) unsigned short Ks[2 * 64 * 64];   // [buf][key][d]
  __shared__ __align__(16) unsigned short Vs[2 * 64 * 64];   // [buf][d][key]

  const int tid = threadIdx.x, lane = tid & 63, w = tid >> 6;   // w: 0..7
  const int l31 = lane & 31, hh = lane >> 5;
  const int qt = blockIdx.x, h = blockIdx.y, b = blockIdx.z;

  const int total = cnt[b] + M_;            // live keys incl. memory slots
  const int nt = (total + 63) >> 6;         // tiles (<= 33)

  const int r0 = tid >> 3, c0 = tid & 7;          // staging: row 0..63, chunk 0..7
  const int ck = c0 ^ (r0 & 7);                   // swizzled chunk
  const unsigned short* Kg = Kb + (size_t)b * SKM * D_ + (size_t)h * HD_;
  const unsigned short* Vg = VtG + (size_t)(b * H_ + h) * HD_ * SKM;

  // Q fragments (B-operand of swapped QK^T): Q[q][ds*16 + hh*8 + i]
  const unsigned short* qp = Qb + ((size_t)(b * S_) + qt * 256 + w * 32 + l31) * D_ + h * HD_;
  s16x8 qf[4];
#pragma unroll
  for (int ds = 0; ds < 4; ds++) qf[ds] = *(const s16x8*)&qp[ds * 16 + hh * 8];

  f32x16 accO[2];
#pragma unroll
  for (int dt = 0; dt < 2; dt++)
#pragma unroll
    for (int j = 0; j < 16; j++) accO[dt][j] = 0.f;
  float m_r = -1e20f, l_r = 0.f;

  uint4 kr0, vr0;
  auto LOAD = [&](int kt) {   // rows < nt*64 <= 2112, always in-bounds
    kr0 = *(const uint4*)&Kg[(size_t)(kt * 64 + r0) * D_ + c0 * 8];
    vr0 = *(const uint4*)&Vg[(size_t)r0 * SKM + kt * 64 + c0 * 8];
  };

  LOAD(0);
  *(uint4*)&Ks[r0 * 64 + ck * 8] = kr0;
  *(uint4*)&Vs[r0 * 64 + ck * 8] = vr0;
  __syncthreads();
  int cur = 0;

  for (int kt = 0; kt < nt; ++kt) {
    const bool pre = (kt + 1 < nt);
    if (pre) LOAD(kt + 1);           // issue-early: lands during compute below

    // ---- S^T = K · Q^T : p0 = keys 0..31, p1 = keys 32..63 (lane: q=l31) ----
    const unsigned short* Kc = &Ks[cur * 4096];
    const unsigned short* Vc = &Vs[cur * 4096];
    f32x16 p0, p1;
#pragma unroll
    for (int j = 0; j < 16; j++) { p0[j] = 0.f; p1[j] = 0.f; }
    __builtin_amdgcn_s_setprio(1);
#pragma unroll
    for (int ds = 0; ds < 4; ds++) {
      s16x8 ka0 = *(const s16x8*)&Kc[l31 * 64 + (((ds * 2 + hh) ^ (l31 & 7)) << 3)];
      s16x8 ka1 = *(const s16x8*)&Kc[(32 + l31) * 64 + (((ds * 2 + hh) ^ (l31 & 7)) << 3)];
      p0 = __builtin_amdgcn_mfma_f32_32x32x16_bf16(ka0, qf[ds], p0, 0, 0, 0);
      p1 = __builtin_amdgcn_mfma_f32_32x32x16_bf16(ka1, qf[ds], p1, 0, 0, 0);
    }
    __builtin_amdgcn_s_setprio(0);

    // ---- tail tile: kill keys beyond `total` (key = (j&3)+8*(j>>2)+4*hh) ----
    if (kt == nt - 1) {
      int valid = total - kt * 64;   // 1..64
#pragma unroll
      for (int j = 0; j < 16; j++) {
        int kl = (j & 3) + 8 * (j >> 2) + 4 * hh;
        if (kl >= valid) p0[j] = -1e30f;
        if (kl + 32 >= valid) p1[j] = -1e30f;
      }
    }

    // ---- online softmax in log2 units, defer-max (T13, THR=8) ----
    float vmax = fmaxf(p0[0], p1[0]);
#pragma unroll
    for (int j = 1; j < 16; j++) vmax = fmaxf(vmax, fmaxf(p0[j], p1[j]));
    vmax = fmaxf(vmax, __shfl_xor(vmax, 32));
    if (!__all(vmax - m_r <= 8.0f)) {
      float mnew = fmaxf(m_r, vmax);
      float fac = __builtin_amdgcn_exp2f(m_r - mnew);
      m_r = mnew;
      l_r *= fac;
#pragma unroll
      for (int dt = 0; dt < 2; dt++)
#pragma unroll
        for (int j = 0; j < 16; j++) accO[dt][j] *= fac;
    }
    float sum = 0.f;
#pragma unroll
    for (int j = 0; j < 16; j++) {
      p0[j] = __builtin_amdgcn_exp2f(p0[j] - m_r); sum += p0[j];
      p1[j] = __builtin_amdgcn_exp2f(p1[j] - m_r); sum += p1[j];
    }
    sum += __shfl_xor(sum, 32);
    l_r += sum;

    // ---- build P^T fragments: frag[ks] = P[q][16ks + hh*8 + 0..7] as bf16x8 ----
    s16x8 pf_[4];
#pragma unroll
    for (int ks = 0; ks < 4; ks++) {
      const int base = (ks & 1) * 8;
#define ELT(t) ((ks >= 2) ? p1[base + (t)] : p0[base + (t)])
      unsigned w0 = pkbf(ELT(0), ELT(1));
      unsigned w1 = pkbf(ELT(2), ELT(3));
      unsigned w2 = pkbf(ELT(4), ELT(5));
      unsigned w3 = pkbf(ELT(6), ELT(7));
#undef ELT
      unsigned s0 = hh ? w0 : w2;         // h0 sends keys {8..11}, h1 sends {4..7}
      unsigned s1 = hh ? w1 : w3;
      unsigned g0 = (unsigned)__shfl_xor((int)s0, 32);
      unsigned g1 = (unsigned)__shfl_xor((int)s1, 32);
      union { s16x8 v; unsigned u[4]; } pf;
      pf.u[0] = hh ? g0 : w0;
      pf.u[1] = hh ? g1 : w1;
      pf.u[2] = hh ? w2 : g0;
      pf.u[3] = hh ? w3 : g1;
      pf_[ks] = pf.v;
    }

    // ---- O^T += V^T · P^T  (row d = dt*32+(j&3)+8*(j>>2)+4*hh, col q = l31) ----
    __builtin_amdgcn_s_setprio(1);
#pragma unroll
    for (int dt = 0; dt < 2; dt++)
#pragma unroll
      for (int ks = 0; ks < 4; ks++) {
        s16x8 va = *(const s16x8*)&Vc[(dt * 32 + l31) * 64 + (((ks * 2 + hh) ^ (l31 & 7)) << 3)];
        accO[dt] = __builtin_amdgcn_mfma_f32_32x32x16_bf16(va, pf_[ks], accO[dt], 0, 0, 0);
      }
    __builtin_amdgcn_s_setprio(0);

    // ---- write-late: stage tile kt+1 into buf^1 (no reader this iter) -------
    if (pre) {
      *(uint4*)&Ks[(cur ^ 1) * 4096 + r0 * 64 + ck * 8] = kr0;
      *(uint4*)&Vs[(cur ^ 1) * 4096 + r0 * 64 + ck * 8] = vr0;
      __syncthreads();               // ONE barrier per tile
      cur ^= 1;
    }
  }

  float invl = 1.0f / l_r;
  size_t orow = ((size_t)(b * S_) + qt * 256 + w * 32 + l31) * D_ + h * HD_;
#pragma unroll
  for (int dt = 0; dt < 2; dt++)
#pragma unroll
    for (int j = 0; j < 16; j++) {
      int d = dt * 32 + (j & 3) + 8 * (j >> 2) + 4 * hh;
      Xb[orow + d] = f2bf(accO[dt][j] * invl);
    }
}

// ------------------------------- launcher -------------------------------------
extern "C" void kernel_launch(void* const* d_in, const int* in_sizes, int n_in,
                              void* d_out, int out_size, void* d_ws, size_t ws_size,
                              hipStream_t stream) {
  const float* query = (const float*)d_in[0];
  const float* key   = (const float*)d_in[1];
  const float* value = (const float*)d_in[2];
  const int*   mask  = (const int*)d_in[3];
  const float* Wq    = (const float*)d_in[4];
  const float* bq    = (const float*)d_in[5];
  const float* Wk    = (const float*)d_in[6];
  const float* bk    = (const float*)d_in[7];
  const float* Wv    = (const float*)d_in[8];
  const float* bv    = (const float*)d_in[9];
  const float* Wo    = (const float*)d_in[10];
  const float* bo    = (const float*)d_in[11];
  const float* m_k   = (const float*)d_in[12];
  const float* m_v   = (const float*)d_in[13];

  const int NQ = B_ * S_ * D_;     // 4,194,304
  const int NW = D_ * D_;          // 1,048,576 = 2^20
  const int NK = B_ * SKM * D_;    // 4,325,376

  unsigned short* ws = (unsigned short*)d_ws;   // ~67.6 MB + 16 KB
  unsigned short* qf = ws;
  unsigned short* kf = qf + NQ;
  unsigned short* vf = kf + NQ;
  unsigned short* wq = vf + NQ;
  unsigned short* wk = wq + NW;
  unsigned short* wv = wk + NW;
  unsigned short* wo = wv + NW;
  unsigned short* Qb = wo + NW;
  unsigned short* Kb = Qb + NQ;
  unsigned short* Vt = Kb + NK;    // [b][h][d][key]
  unsigned short* Xb = Vt + NK;
  int* idx = (int*)(Xb + NQ);      // [B][S]
  int* cnt = idx + B_ * S_;        // [B]

  compact_mask<<<B_, 256, 0, stream>>>(mask, idx, cnt);
  // one launch: query+weights linear cvt (8192 blocks) + K/V gather (8192)
  cvt_fused<<<16384, 256, 0, stream>>>(query, Wq, Wk, Wv, Wo, key, value,
                                       qf, wq, wk, wv, wo, kf, vf, idx, cnt);

  // merged Q/K/V projection, BK=64 core (half the K-steps of R12)
  gemm_qkv<<<768, 512, 0, stream>>>(qf, kf, vf, wq, wk, wv, bq, bk, bv, Qb, Kb, Vt, cnt);
  // memory rows appended at key position cnt[b] — must run AFTER K/V GEMMs
  fill_mem<<<(M_ * D_) / 256, 256, 0, stream>>>(m_k, m_v, Kb, Vt, cnt);

  attn_kernel<<<dim3(S_ / 256, H_, B_), 512, 0, stream>>>(Qb, Kb, Vt, cnt, Xb);

  gemm_o<<<256, 512, 0, stream>>>(Xb, wo, bo, (float*)d_out);
}

// Round 19
// 122.405 us; speedup vs baseline: 1.0511x; 1.0038x over previous
//
#include <hip/hip_runtime.h>
#include <hip/hip_bf16.h>
#include <stdint.h>

// Problem constants (B,S,D,H,M) = (2,2048,1024,16,64), HD=64
#define B_  2
#define S_  2048
#define D_  1024
#define H_  16
#define HD_ 64
#define M_  64
#define SKM (S_ + M_)   // 2112
#define LOG2E 1.44269504088896340736f

typedef __attribute__((ext_vector_type(8))) short s16x8;
typedef __attribute__((ext_vector_type(4))) float f32x4;
typedef __attribute__((ext_vector_type(16))) float f32x16;

// global_load_lds width=16: linear LDS dest (base + lane*16), per-lane global src
#define GLOAD16(gp, lp) __builtin_amdgcn_global_load_lds( \
    (const __attribute__((address_space(1))) void*)(gp),  \
    (__attribute__((address_space(3))) void*)(lp), 16, 0, 0)

// counted vmcnt wait (T4): literal N, then pin scheduler (rule #18)
#define WAITVM(N) do { asm volatile("s_waitcnt vmcnt(" #N ")" ::: "memory"); \
                       __builtin_amdgcn_sched_barrier(0); } while (0)
// raw s_barrier WITHOUT the __syncthreads vmcnt(0) drain
#define BARRIER() do { asm volatile("" ::: "memory"); \
                       __builtin_amdgcn_s_barrier(); \
                       asm volatile("" ::: "memory"); } while (0)

__device__ __forceinline__ unsigned short f2bf(float f) {
  union { float f; unsigned int u; } v; v.f = f;
  unsigned int r = v.u + 0x7fffu + ((v.u >> 16) & 1u);  // RNE
  return (unsigned short)(r >> 16);
}

__device__ __forceinline__ unsigned pkbf(float lo, float hi) {
  union { __hip_bfloat162 b; unsigned u; } t;
  t.b = __float22bfloat162_rn(make_float2(lo, hi));   // -> v_cvt_pk_bf16_f32
  return t.u;
}

// ---- mask compaction: idx[b][j] = j-th unmasked key, cnt[b] = count ----------
// 1024 threads: 2 scan iterations over S_=2048 (was 8 with 256 threads).
__global__ void compact_mask(const int* __restrict__ mask,
                             int* __restrict__ idx, int* __restrict__ cnt) {
  const int b = blockIdx.x;
  __shared__ int base, wsum[16];
  if (threadIdx.x == 0) base = 0;
  const int lane = threadIdx.x & 63, w = threadIdx.x >> 6;   // w: 0..15
  __syncthreads();
  for (int c = 0; c < S_; c += 1024) {
    int key = c + threadIdx.x;
    int mv = mask[b * S_ + key];
    unsigned long long bal = __ballot(mv != 0);
    int pre = __popcll(bal & ((1ull << lane) - 1ull));
    if (lane == 0) wsum[w] = __popcll(bal);
    __syncthreads();
    int woff = 0;
#pragma unroll
    for (int i = 0; i < 16; i++) woff += (i < w) ? wsum[i] : 0;
    int tot = 0;
#pragma unroll
    for (int i = 0; i < 16; i++) tot += wsum[i];
    if (mv) idx[b * S_ + base + woff + pre] = key;
    __syncthreads();
    if (threadIdx.x == 0) base += tot;
    __syncthreads();
  }
  if (threadIdx.x == 0) cnt[b] = base;
}

// ---- ALL conversions in ONE launch: query + 4 weights + K/V gather -----------
__global__ void cvt_fused(const float* __restrict__ q,
                          const float* __restrict__ w0, const float* __restrict__ w1,
                          const float* __restrict__ w2, const float* __restrict__ w3,
                          const float* __restrict__ key, const float* __restrict__ value,
                          unsigned short* __restrict__ qf,
                          unsigned short* __restrict__ o0, unsigned short* __restrict__ o1,
                          unsigned short* __restrict__ o2, unsigned short* __restrict__ o3,
                          unsigned short* __restrict__ kf, unsigned short* __restrict__ vf,
                          const int* __restrict__ idx, const int* __restrict__ cnt) {
  const size_t NQs = (size_t)B_ * S_ * D_;
  if (blockIdx.x < 8192) {
    size_t i = ((size_t)blockIdx.x * 256 + threadIdx.x) * 4;
    const float* in; unsigned short* out; size_t off;
    if (i < NQs) { in = q; out = qf; off = i; }
    else {
      size_t j = i - NQs;
      int wsel = (int)(j >> 20);
      off = j & ((1u << 20) - 1);
      in  = (wsel == 0) ? w0 : (wsel == 1) ? w1 : (wsel == 2) ? w2 : w3;
      out = (wsel == 0) ? o0 : (wsel == 1) ? o1 : (wsel == 2) ? o2 : o3;
    }
    float4 v = *(const float4*)&in[off];
    ushort4 o;
    o.x = f2bf(v.x); o.y = f2bf(v.y); o.z = f2bf(v.z); o.w = f2bf(v.w);
    *(ushort4*)&out[off] = o;
  } else {
    int gid = blockIdx.x - 8192;         // [0, 8192)
    int kv = gid >> 12, rem = gid & 4095;
    int b = rem >> 11, j = rem & 2047;
    if (j >= cnt[b]) return;
    const float* in = kv ? value : key;
    unsigned short* out = kv ? vf : kf;
    int src = idx[b * S_ + j];
    const float* ip = in + ((size_t)(b * S_) + src) * D_;
    unsigned short* op = out + ((size_t)(b * S_) + j) * D_;
    int t = threadIdx.x * 4;
    float4 v = *(const float4*)&ip[t];
    ushort4 o;
    o.x = f2bf(v.x); o.y = f2bf(v.y); o.z = f2bf(v.z); o.w = f2bf(v.w);
    *(ushort4*)&op[t] = o;
  }
}

// ---- memory rows appended at key position cnt[b] (AFTER the K/V GEMMs) -------
__global__ void fill_mem(const float* __restrict__ mk, const float* __restrict__ mv,
                         unsigned short* __restrict__ Kb, unsigned short* __restrict__ VtG,
                         const int* __restrict__ cnt) {
  int i = blockIdx.x * 256 + threadIdx.x;     // 0 .. M_*D_-1
  int row = i >> 10, col = i & 1023;
  int hI = col >> 6, dd = col & 63;
  unsigned short kv = f2bf(8.0f * mk[i]);
  unsigned short vv = f2bf(8.0f * mv[i]);
#pragma unroll
  for (int b = 0; b < B_; b++) {
    int c = cnt[b];
    Kb[((size_t)(b * SKM) + c + row) * D_ + col] = kv;
    VtG[((size_t)(b * H_ + hI) * HD_ + dd) * SKM + c + row] = vv;
  }
}

// ------ GEMM: R18 core, BK=64. 128x128 tile, 8 waves (64x32/wave), ------------
// 2 buffers, TWO barriers per K-step, counted WAITVM(4).
// Swizzle (rule #21 both-sides, 8 chunks): LDS[r][c] = global[r][c ^ (r&7)].
__device__ __forceinline__ void gemm_core64(
    const unsigned short* __restrict__ A,
    const unsigned short* __restrict__ Bw,
    unsigned short* As, unsigned short* Bs,   // each 2*128*64 elems (32 KB)
    int mBase, int nBase,
    int tid, f32x4 acc[4][2]) {
  const int lane = tid & 63, w = tid >> 6;          // w: 0..7
  const int wr = w >> 2, wc = w & 3;                // wave grid 2x4 (64x32 each)
  const int lr = lane & 15, lk = lane >> 4;
  const int rg = lane >> 3;                         // row-in-8 (0..7)
  const int sr0 = w * 8 + rg;                       // staging rows sr0, sr0+64
  const int ca = (lane & 7) ^ (rg & 7);             // inverse-swizzled src chunk
  const int NT = D_ / 64;                           // 16

#define STAGE_(buf, k0)                                                          \
  {                                                                              \
    GLOAD16(&A[(size_t)(mBase + sr0) * D_ + (k0) + ca * 8],                      \
            &As[(buf) * (128 * 64) + (w * 8) * 64]);                             \
    GLOAD16(&A[(size_t)(mBase + 64 + sr0) * D_ + (k0) + ca * 8],                 \
            &As[(buf) * (128 * 64) + (64 + w * 8) * 64]);                        \
    GLOAD16(&Bw[(size_t)(nBase + sr0) * D_ + (k0) + ca * 8],                     \
            &Bs[(buf) * (128 * 64) + (w * 8) * 64]);                             \
    GLOAD16(&Bw[(size_t)(nBase + 64 + sr0) * D_ + (k0) + ca * 8],                \
            &Bs[(buf) * (128 * 64) + (64 + w * 8) * 64]);                        \
  }

  STAGE_(0, 0);                              // 4 loads in flight
  int cur = 0;
  for (int t = 0; t < NT; ++t) {
    if (t + 1 < NT) {
      STAGE_(cur ^ 1, (t + 1) * 64);         // 8 in flight
      WAITVM(4);                             // tile t's 4 done; t+1's in flight
    } else {
      WAITVM(0);
    }
    BARRIER();                               // all waves: tile t staged
#pragma unroll
    for (int ks = 0; ks < 2; ks++) {
      s16x8 af[4], bf[2];
#pragma unroll
      for (int mi = 0; mi < 4; mi++) {
        int row = wr * 64 + mi * 16 + lr;
        af[mi] = *(const s16x8*)&As[cur * (128 * 64) + row * 64 + (((ks * 4 + lk) ^ (row & 7)) << 3)];
      }
#pragma unroll
      for (int ni = 0; ni < 2; ni++) {
        int row = wc * 32 + ni * 16 + lr;
        bf[ni] = *(const s16x8*)&Bs[cur * (128 * 64) + row * 64 + (((ks * 4 + lk) ^ (row & 7)) << 3)];
      }
#pragma unroll
      for (int mi = 0; mi < 4; mi++)
#pragma unroll
        for (int ni = 0; ni < 2; ni++)
          acc[mi][ni] = __builtin_amdgcn_mfma_f32_16x16x32_bf16(af[mi], bf[ni], acc[mi][ni], 0, 0, 0);
    }
    BARRIER();   // all waves' reads of buf[cur] latched -> safe to re-stage it
    cur ^= 1;
  }
#undef STAGE_
}

// ---- merged Q/K/V projection, 1D grid 768, XCD-chunked work swizzle ----------
__global__ __launch_bounds__(512)
void gemm_qkv(const unsigned short* __restrict__ qf, const unsigned short* __restrict__ kf,
              const unsigned short* __restrict__ vf,
              const unsigned short* __restrict__ wq, const unsigned short* __restrict__ wk,
              const unsigned short* __restrict__ wv,
              const float* __restrict__ bq, const float* __restrict__ bk,
              const float* __restrict__ bv,
              unsigned short* __restrict__ Qb, unsigned short* __restrict__ Kb,
              unsigned short* __restrict__ Vt,
              const int* __restrict__ cnt) {
  __shared__ __align__(16) unsigned short As[2 * 128 * 64];
  __shared__ __align__(16) unsigned short Bs[2 * 128 * 64];
  // T1: within each z-slice of 256 works, XCD (bid&7) owns 32 contiguous works
  const int z = blockIdx.x >> 8;
  const int local = blockIdx.x & 255;
  const int wsz = (local & 7) * 32 + (local >> 3);   // bijective (256 = 8*32)
  const int nBase = (wsz & 7) * 128, mBase = (wsz >> 3) * 128;
  const int bb = (mBase >= S_);
  if (z) {   // K/V: skip tiles entirely beyond the compacted row count
    if (mBase - bb * S_ >= cnt[bb]) return;
  }
  const unsigned short* A  = (z == 0) ? qf : (z == 1) ? kf : vf;
  const unsigned short* Bw = (z == 0) ? wq : (z == 1) ? wk : wv;
  const float* bias        = (z == 0) ? bq : (z == 1) ? bk : bv;

  const int tid = threadIdx.x, lane = tid & 63;
  const int w = tid >> 6, wr = w >> 2, wc = w & 3;
  const int lr = lane & 15, lk = lane >> 4;

  const f32x4 fz = {0.f, 0.f, 0.f, 0.f};
  f32x4 acc[4][2];
#pragma unroll
  for (int i = 0; i < 4; i++)
#pragma unroll
    for (int j = 0; j < 2; j++) acc[i][j] = fz;

  gemm_core64(A, Bw, As, Bs, mBase, nBase, tid, acc);

  const float alpha = (z == 0) ? 0.125f * LOG2E : 1.0f;   // Q: 1/sqrt(HD) * log2(e)
#pragma unroll
  for (int mi = 0; mi < 4; mi++)
#pragma unroll
    for (int ni = 0; ni < 2; ni++)
#pragma unroll
      for (int r = 0; r < 4; r++) {
        int gr = mBase + wr * 64 + mi * 16 + lk * 4 + r;
        int gc = nBase + wc * 32 + ni * 16 + lr;
        float v = (acc[mi][ni][r] + bias[gc]) * alpha;
        if (z == 2) {        // V^T: [b][h][d][key]
          int s = gr - bb * S_;
          int hI = gc >> 6, dd = gc & 63;
          Vt[((size_t)(bb * H_ + hI) * HD_ + dd) * SKM + s] = f2bf(v);
        } else if (z == 1) { // K rows with per-batch mem-row gap
          int orow = gr + bb * M_;
          Kb[(size_t)orow * D_ + gc] = f2bf(v);
        } else {
          Qb[(size_t)gr * D_ + gc] = f2bf(v);
        }
      }
}

// ---- output projection: f32 out, BK=64 core ----------------------------------
__global__ __launch_bounds__(512)
void gemm_o(const unsigned short* __restrict__ A, const unsigned short* __restrict__ Bw,
            const float* __restrict__ bias, float* __restrict__ Cout) {
  __shared__ __align__(16) unsigned short As[2 * 128 * 64];
  __shared__ __align__(16) unsigned short Bs[2 * 128 * 64];
  const int local = blockIdx.x & 255;
  const int wsz = (local & 7) * 32 + (local >> 3);
  const int nBase = (wsz & 7) * 128, mBase = (wsz >> 3) * 128;
  const int tid = threadIdx.x, lane = tid & 63;
  const int w = tid >> 6, wr = w >> 2, wc = w & 3;
  const int lr = lane & 15, lk = lane >> 4;

  const f32x4 fz = {0.f, 0.f, 0.f, 0.f};
  f32x4 acc[4][2];
#pragma unroll
  for (int i = 0; i < 4; i++)
#pragma unroll
    for (int j = 0; j < 2; j++) acc[i][j] = fz;

  gemm_core64(A, Bw, As, Bs, mBase, nBase, tid, acc);

#pragma unroll
  for (int mi = 0; mi < 4; mi++)
#pragma unroll
    for (int ni = 0; ni < 2; ni++)
#pragma unroll
      for (int r = 0; r < 4; r++) {
        int gr = mBase + wr * 64 + mi * 16 + lk * 4 + r;
        int gc = nBase + wc * 32 + ni * 16 + lr;
        Cout[(size_t)gr * D_ + gc] = acc[mi][ni][r] + bias[gc];
      }
}

// -------- Flash attention: PAIRED 64-key sub-tiles, ONE barrier per 128 keys --
// Block: 256 q-rows (8 waves x 32) for one (b,h). Double-buffered pairs:
// LOAD(pair+1) issued BEFORE compute (clamped to last tile; dup data is killed
// by tail masking); two sub-tile compute passes (registers reused); ds_write
// AFTER compute into buf^1; single __syncthreads per pair.
__global__ __launch_bounds__(512)
void attn_kernel(const unsigned short* __restrict__ Qb,
                 const unsigned short* __restrict__ Kb,
                 const unsigned short* __restrict__ VtG,
                 const int* __restrict__ cnt,
                 unsigned short* __restrict__ Xb) {
  __shared__ __align__(16) unsigned short Ks[2 * 2 * 64 * 64];   // [buf][sub][key][d]
  __shared__ __align__(16) unsigned short Vs[2 * 2 * 64 * 64];   // [buf][sub][d][key]

  const int tid = threadIdx.x, lane = tid & 63, w = tid >> 6;   // w: 0..7
  const int l31 = lane & 31, hh = lane >> 5;
  const int qt = blockIdx.x, h = blockIdx.y, b = blockIdx.z;

  const int total = cnt[b] + M_;            // live keys incl. memory slots
  const int nt = (total + 63) >> 6;         // 64-key tiles (<= 33)
  const int npair = (nt + 1) >> 1;

  const int r0 = tid >> 3, c0 = tid & 7;          // staging: row 0..63, chunk 0..7
  const int ck = c0 ^ (r0 & 7);                   // swizzled chunk
  const unsigned short* Kg = Kb + (size_t)b * SKM * D_ + (size_t)h * HD_;
  const unsigned short* Vg = VtG + (size_t)(b * H_ + h) * HD_ * SKM;

  // Q fragments (B-operand of swapped QK^T): Q[q][ds*16 + hh*8 + i]
  const unsigned short* qp = Qb + ((size_t)(b * S_) + qt * 256 + w * 32 + l31) * D_ + h * HD_;
  s16x8 qf[4];
#pragma unroll
  for (int ds = 0; ds < 4; ds++) qf[ds] = *(const s16x8*)&qp[ds * 16 + hh * 8];

  f32x16 accO[2];
#pragma unroll
  for (int dt = 0; dt < 2; dt++)
#pragma unroll
    for (int j = 0; j < 16; j++) accO[dt][j] = 0.f;
  float m_r = -1e20f, l_r = 0.f;

  uint4 kr0, kr1, vr0, vr1;
  auto LOAD = [&](int pair) {   // tiles 2p, 2p+1 clamped to nt-1 (dup masked)
    int t0 = pair * 2;     if (t0 > nt - 1) t0 = nt - 1;
    int t1 = pair * 2 + 1; if (t1 > nt - 1) t1 = nt - 1;
    kr0 = *(const uint4*)&Kg[(size_t)(t0 * 64 + r0) * D_ + c0 * 8];
    kr1 = *(const uint4*)&Kg[(size_t)(t1 * 64 + r0) * D_ + c0 * 8];
    vr0 = *(const uint4*)&Vg[(size_t)r0 * SKM + t0 * 64 + c0 * 8];
    vr1 = *(const uint4*)&Vg[(size_t)r0 * SKM + t1 * 64 + c0 * 8];
  };

  LOAD(0);
  *(uint4*)&Ks[r0 * 64 + ck * 8] = kr0;
  *(uint4*)&Ks[4096 + r0 * 64 + ck * 8] = kr1;
  *(uint4*)&Vs[r0 * 64 + ck * 8] = vr0;
  *(uint4*)&Vs[4096 + r0 * 64 + ck * 8] = vr1;
  __syncthreads();
  int cur = 0;

  for (int p = 0; p < npair; ++p) {
    const bool pre = (p + 1 < npair);
    if (pre) LOAD(p + 1);            // issue-early: lands during compute below

#pragma unroll
    for (int s = 0; s < 2; s++) {
      const int kt = p * 2 + s;
      if (kt >= nt) break;           // uniform (nt is block-uniform)
      const unsigned short* Kc = &Ks[cur * 8192 + s * 4096];
      const unsigned short* Vc = &Vs[cur * 8192 + s * 4096];

      // ---- S^T = K · Q^T : p0 = keys 0..31, p1 = keys 32..63 (q = l31) ----
      f32x16 p0, p1;
#pragma unroll
      for (int j = 0; j < 16; j++) { p0[j] = 0.f; p1[j] = 0.f; }
      __builtin_amdgcn_s_setprio(1);
#pragma unroll
      for (int ds = 0; ds < 4; ds++) {
        s16x8 ka0 = *(const s16x8*)&Kc[l31 * 64 + (((ds * 2 + hh) ^ (l31 & 7)) << 3)];
        s16x8 ka1 = *(const s16x8*)&Kc[(32 + l31) * 64 + (((ds * 2 + hh) ^ (l31 & 7)) << 3)];
        p0 = __builtin_amdgcn_mfma_f32_32x32x16_bf16(ka0, qf[ds], p0, 0, 0, 0);
        p1 = __builtin_amdgcn_mfma_f32_32x32x16_bf16(ka1, qf[ds], p1, 0, 0, 0);
      }
      __builtin_amdgcn_s_setprio(0);

      // ---- tail tile: kill keys beyond `total` (key = (j&3)+8*(j>>2)+4*hh) --
      if (kt == nt - 1) {
        int valid = total - kt * 64;   // 1..64
#pragma unroll
        for (int j = 0; j < 16; j++) {
          int kl = (j & 3) + 8 * (j >> 2) + 4 * hh;
          if (kl >= valid) p0[j] = -1e30f;
          if (kl + 32 >= valid) p1[j] = -1e30f;
        }
      }

      // ---- online softmax in log2 units, defer-max (T13, THR=8) ----
      float vmax = fmaxf(p0[0], p1[0]);
#pragma unroll
      for (int j = 1; j < 16; j++) vmax = fmaxf(vmax, fmaxf(p0[j], p1[j]));
      vmax = fmaxf(vmax, __shfl_xor(vmax, 32));
      if (!__all(vmax - m_r <= 8.0f)) {
        float mnew = fmaxf(m_r, vmax);
        float fac = __builtin_amdgcn_exp2f(m_r - mnew);
        m_r = mnew;
        l_r *= fac;
#pragma unroll
        for (int dt = 0; dt < 2; dt++)
#pragma unroll
          for (int j = 0; j < 16; j++) accO[dt][j] *= fac;
      }
      float sum = 0.f;
#pragma unroll
      for (int j = 0; j < 16; j++) {
        p0[j] = __builtin_amdgcn_exp2f(p0[j] - m_r); sum += p0[j];
        p1[j] = __builtin_amdgcn_exp2f(p1[j] - m_r); sum += p1[j];
      }
      sum += __shfl_xor(sum, 32);
      l_r += sum;

      // ---- build P^T fragments: frag[ks] = P[q][16ks + hh*8 + 0..7] ----
      s16x8 pf_[4];
#pragma unroll
      for (int ks = 0; ks < 4; ks++) {
        const int base = (ks & 1) * 8;
#define ELT(t) ((ks >= 2) ? p1[base + (t)] : p0[base + (t)])
        unsigned w0 = pkbf(ELT(0), ELT(1));
        unsigned w1 = pkbf(ELT(2), ELT(3));
        unsigned w2 = pkbf(ELT(4), ELT(5));
        unsigned w3 = pkbf(ELT(6), ELT(7));
#undef ELT
        unsigned s0 = hh ? w0 : w2;       // h0 sends keys {8..11}, h1 sends {4..7}
        unsigned s1 = hh ? w1 : w3;
        unsigned g0 = (unsigned)__shfl_xor((int)s0, 32);
        unsigned g1 = (unsigned)__shfl_xor((int)s1, 32);
        union { s16x8 v; unsigned u[4]; } pf;
        pf.u[0] = hh ? g0 : w0;
        pf.u[1] = hh ? g1 : w1;
        pf.u[2] = hh ? w2 : g0;
        pf.u[3] = hh ? w3 : g1;
        pf_[ks] = pf.v;
      }

      // ---- O^T += V^T · P^T  (row d = dt*32+(j&3)+8*(j>>2)+4*hh, q = l31) ---
      __builtin_amdgcn_s_setprio(1);
#pragma unroll
      for (int dt = 0; dt < 2; dt++)
#pragma unroll
        for (int ks = 0; ks < 4; ks++) {
          s16x8 va = *(const s16x8*)&Vc[(dt * 32 + l31) * 64 + (((ks * 2 + hh) ^ (l31 & 7)) << 3)];
          accO[dt] = __builtin_amdgcn_mfma_f32_32x32x16_bf16(va, pf_[ks], accO[dt], 0, 0, 0);
        }
      __builtin_amdgcn_s_setprio(0);
    }

    // ---- write-late: stage pair p+1 into buf^1 (no reader this iter) --------
    if (pre) {
      int ob = (cur ^ 1) * 8192;
      *(uint4*)&Ks[ob + r0 * 64 + ck * 8] = kr0;
      *(uint4*)&Ks[ob + 4096 + r0 * 64 + ck * 8] = kr1;
      *(uint4*)&Vs[ob + r0 * 64 + ck * 8] = vr0;
      *(uint4*)&Vs[ob + 4096 + r0 * 64 + ck * 8] = vr1;
      __syncthreads();               // ONE barrier per 128 keys
      cur ^= 1;
    }
  }

  float invl = 1.0f / l_r;
  size_t orow = ((size_t)(b * S_) + qt * 256 + w * 32 + l31) * D_ + h * HD_;
#pragma unroll
  for (int dt = 0; dt < 2; dt++)
#pragma unroll
    for (int j = 0; j < 16; j++) {
      int d = dt * 32 + (j & 3) + 8 * (j >> 2) + 4 * hh;
      Xb[orow + d] = f2bf(accO[dt][j] * invl);
    }
}

// ------------------------------- launcher -------------------------------------
extern "C" void kernel_launch(void* const* d_in, const int* in_sizes, int n_in,
                              void* d_out, int out_size, void* d_ws, size_t ws_size,
                              hipStream_t stream) {
  const float* query = (const float*)d_in[0];
  const float* key   = (const float*)d_in[1];
  const float* value = (const float*)d_in[2];
  const int*   mask  = (const int*)d_in[3];
  const float* Wq    = (const float*)d_in[4];
  const float* bq    = (const float*)d_in[5];
  const float* Wk    = (const float*)d_in[6];
  const float* bk    = (const float*)d_in[7];
  const float* Wv    = (const float*)d_in[8];
  const float* bv    = (const float*)d_in[9];
  const float* Wo    = (const float*)d_in[10];
  const float* bo    = (const float*)d_in[11];
  const float* m_k   = (const float*)d_in[12];
  const float* m_v   = (const float*)d_in[13];

  const int NQ = B_ * S_ * D_;     // 4,194,304
  const int NW = D_ * D_;          // 1,048,576 = 2^20
  const int NK = B_ * SKM * D_;    // 4,325,376

  unsigned short* ws = (unsigned short*)d_ws;   // ~67.6 MB + 16 KB
  unsigned short* qf = ws;
  unsigned short* kf = qf + NQ;
  unsigned short* vf = kf + NQ;
  unsigned short* wq = vf + NQ;
  unsigned short* wk = wq + NW;
  unsigned short* wv = wk + NW;
  unsigned short* wo = wv + NW;
  unsigned short* Qb = wo + NW;
  unsigned short* Kb = Qb + NQ;
  unsigned short* Vt = Kb + NK;    // [b][h][d][key]
  unsigned short* Xb = Vt + NK;
  int* idx = (int*)(Xb + NQ);      // [B][S]
  int* cnt = idx + B_ * S_;        // [B]

  compact_mask<<<B_, 1024, 0, stream>>>(mask, idx, cnt);
  // one launch: query+weights linear cvt (8192 blocks) + K/V gather (8192)
  cvt_fused<<<16384, 256, 0, stream>>>(query, Wq, Wk, Wv, Wo, key, value,
                                       qf, wq, wk, wv, wo, kf, vf, idx, cnt);

  // merged Q/K/V projection, BK=64 core
  gemm_qkv<<<768, 512, 0, stream>>>(qf, kf, vf, wq, wk, wv, bq, bk, bv, Qb, Kb, Vt, cnt);
  // memory rows appended at key position cnt[b] — must run AFTER K/V GEMMs
  fill_mem<<<(M_ * D_) / 256, 256, 0, stream>>>(m_k, m_v, Kb, Vt, cnt);

  attn_kernel<<<dim3(S_ / 256, H_, B_), 512, 0, stream>>>(Qb, Kb, Vt, cnt, Xb);

  gemm_o<<<256, 512, 0, stream>>>(Xb, wo, bo, (float*)d_out);
}

// Round 20
// 121.271 us; speedup vs baseline: 1.0610x; 1.0093x over previous
//
#include <hip/hip_runtime.h>
#include <hip/hip_bf16.h>
#include <stdint.h>

// Problem constants (B,S,D,H,M) = (2,2048,1024,16,64), HD=64
#define B_  2
#define S_  2048
#define D_  1024
#define H_  16
#define HD_ 64
#define M_  64
#define SKM (S_ + M_)   // 2112
#define LOG2E 1.44269504088896340736f

typedef __attribute__((ext_vector_type(8))) short s16x8;
typedef __attribute__((ext_vector_type(4))) float f32x4;
typedef __attribute__((ext_vector_type(16))) float f32x16;

// global_load_lds width=16: linear LDS dest (base + lane*16), per-lane global src
#define GLOAD16(gp, lp) __builtin_amdgcn_global_load_lds( \
    (const __attribute__((address_space(1))) void*)(gp),  \
    (__attribute__((address_space(3))) void*)(lp), 16, 0, 0)

// counted vmcnt wait (T4): literal N, then pin scheduler (rule #18)
#define WAITVM(N) do { asm volatile("s_waitcnt vmcnt(" #N ")" ::: "memory"); \
                       __builtin_amdgcn_sched_barrier(0); } while (0)
// raw s_barrier WITHOUT the __syncthreads vmcnt(0) drain
#define BARRIER() do { asm volatile("" ::: "memory"); \
                       __builtin_amdgcn_s_barrier(); \
                       asm volatile("" ::: "memory"); } while (0)

__device__ __forceinline__ unsigned short f2bf(float f) {
  union { float f; unsigned int u; } v; v.f = f;
  unsigned int r = v.u + 0x7fffu + ((v.u >> 16) & 1u);  // RNE
  return (unsigned short)(r >> 16);
}

__device__ __forceinline__ unsigned pkbf(float lo, float hi) {
  union { __hip_bfloat162 b; unsigned u; } t;
  t.b = __float22bfloat162_rn(make_float2(lo, hi));   // -> v_cvt_pk_bf16_f32
  return t.u;
}

// ---- mask compaction: idx[b][j] = j-th unmasked key, cnt[b] = count ----------
__global__ void compact_mask(const int* __restrict__ mask,
                             int* __restrict__ idx, int* __restrict__ cnt) {
  const int b = blockIdx.x;
  __shared__ int base, wsum[16];
  if (threadIdx.x == 0) base = 0;
  const int lane = threadIdx.x & 63, w = threadIdx.x >> 6;   // w: 0..15
  __syncthreads();
  for (int c = 0; c < S_; c += 1024) {
    int key = c + threadIdx.x;
    int mv = mask[b * S_ + key];
    unsigned long long bal = __ballot(mv != 0);
    int pre = __popcll(bal & ((1ull << lane) - 1ull));
    if (lane == 0) wsum[w] = __popcll(bal);
    __syncthreads();
    int woff = 0;
#pragma unroll
    for (int i = 0; i < 16; i++) woff += (i < w) ? wsum[i] : 0;
    int tot = 0;
#pragma unroll
    for (int i = 0; i < 16; i++) tot += wsum[i];
    if (mv) idx[b * S_ + base + woff + pre] = key;
    __syncthreads();
    if (threadIdx.x == 0) base += tot;
    __syncthreads();
  }
  if (threadIdx.x == 0) cnt[b] = base;
}

// ---- ALL conversions in ONE launch: query + 4 weights + K/V gather -----------
__global__ void cvt_fused(const float* __restrict__ q,
                          const float* __restrict__ w0, const float* __restrict__ w1,
                          const float* __restrict__ w2, const float* __restrict__ w3,
                          const float* __restrict__ key, const float* __restrict__ value,
                          unsigned short* __restrict__ qf,
                          unsigned short* __restrict__ o0, unsigned short* __restrict__ o1,
                          unsigned short* __restrict__ o2, unsigned short* __restrict__ o3,
                          unsigned short* __restrict__ kf, unsigned short* __restrict__ vf,
                          const int* __restrict__ idx, const int* __restrict__ cnt) {
  const size_t NQs = (size_t)B_ * S_ * D_;
  if (blockIdx.x < 8192) {
    size_t i = ((size_t)blockIdx.x * 256 + threadIdx.x) * 4;
    const float* in; unsigned short* out; size_t off;
    if (i < NQs) { in = q; out = qf; off = i; }
    else {
      size_t j = i - NQs;
      int wsel = (int)(j >> 20);
      off = j & ((1u << 20) - 1);
      in  = (wsel == 0) ? w0 : (wsel == 1) ? w1 : (wsel == 2) ? w2 : w3;
      out = (wsel == 0) ? o0 : (wsel == 1) ? o1 : (wsel == 2) ? o2 : o3;
    }
    float4 v = *(const float4*)&in[off];
    ushort4 o;
    o.x = f2bf(v.x); o.y = f2bf(v.y); o.z = f2bf(v.z); o.w = f2bf(v.w);
    *(ushort4*)&out[off] = o;
  } else {
    int gid = blockIdx.x - 8192;         // [0, 8192)
    int kv = gid >> 12, rem = gid & 4095;
    int b = rem >> 11, j = rem & 2047;
    if (j >= cnt[b]) return;
    const float* in = kv ? value : key;
    unsigned short* out = kv ? vf : kf;
    int src = idx[b * S_ + j];
    const float* ip = in + ((size_t)(b * S_) + src) * D_;
    unsigned short* op = out + ((size_t)(b * S_) + j) * D_;
    int t = threadIdx.x * 4;
    float4 v = *(const float4*)&ip[t];
    ushort4 o;
    o.x = f2bf(v.x); o.y = f2bf(v.y); o.z = f2bf(v.z); o.w = f2bf(v.w);
    *(ushort4*)&op[t] = o;
  }
}

// ---- memory rows appended at key position cnt[b] (AFTER the K/V GEMMs) -------
__global__ void fill_mem(const float* __restrict__ mk, const float* __restrict__ mv,
                         unsigned short* __restrict__ Kb, unsigned short* __restrict__ VtG,
                         const int* __restrict__ cnt) {
  int i = blockIdx.x * 256 + threadIdx.x;     // 0 .. M_*D_-1
  int row = i >> 10, col = i & 1023;
  int hI = col >> 6, dd = col & 63;
  unsigned short kv = f2bf(8.0f * mk[i]);
  unsigned short vv = f2bf(8.0f * mv[i]);
#pragma unroll
  for (int b = 0; b < B_; b++) {
    int c = cnt[b];
    Kb[((size_t)(b * SKM) + c + row) * D_ + col] = kv;
    VtG[((size_t)(b * H_ + hI) * HD_ + dd) * SKM + c + row] = vv;
  }
}

// ------ gemm_qkv: R17/R12 BK=32 core (best measured 44.6 us tight). ----------
// 128x128 tile, 8 waves (64x32/wave), 2 buffers, TWO barriers per K-step,
// counted WAITVM(2). LDS 32 KB. Swizzle: LDS[r][c] = global[r][c^((r>>1)&3)].
__global__ __launch_bounds__(512)
void gemm_qkv(const unsigned short* __restrict__ qf, const unsigned short* __restrict__ kf,
              const unsigned short* __restrict__ vf,
              const unsigned short* __restrict__ wq, const unsigned short* __restrict__ wk,
              const unsigned short* __restrict__ wv,
              const float* __restrict__ bq, const float* __restrict__ bk,
              const float* __restrict__ bv,
              unsigned short* __restrict__ Qb, unsigned short* __restrict__ Kb,
              unsigned short* __restrict__ Vt,
              const int* __restrict__ cnt) {
  __shared__ __align__(16) unsigned short As[2 * 128 * 32];
  __shared__ __align__(16) unsigned short Bs[2 * 128 * 32];
  // T1: within each z-slice of 256 works, XCD (bid&7) owns 32 contiguous works
  const int z = blockIdx.x >> 8;
  const int local = blockIdx.x & 255;
  const int wsz = (local & 7) * 32 + (local >> 3);   // bijective (256 = 8*32)
  const int nBase = (wsz & 7) * 128, mBase = (wsz >> 3) * 128;
  const int bb = (mBase >= S_);
  if (z) {   // K/V: skip tiles entirely beyond the compacted row count
    if (mBase - bb * S_ >= cnt[bb]) return;
  }
  const unsigned short* A  = (z == 0) ? qf : (z == 1) ? kf : vf;
  const unsigned short* Bw = (z == 0) ? wq : (z == 1) ? wk : wv;
  const float* bias        = (z == 0) ? bq : (z == 1) ? bk : bv;

  const int tid = threadIdx.x, lane = tid & 63;
  const int w = tid >> 6;                  // 0..7
  const int wr = w >> 2, wc = w & 3;       // 2x4 wave grid, 64x32 per wave
  const int lr = lane & 15, lk = lane >> 4;
  const int srow = tid >> 2;               // staging row 0..127
  const int cd = tid & 3;                  // dest chunk (linear)
  const int ca = cd ^ ((srow >> 1) & 3);   // inverse-swizzled source chunk
  const int NT = D_ / 32;                  // 32

  const f32x4 fz = {0.f, 0.f, 0.f, 0.f};
  f32x4 acc[4][2];
#pragma unroll
  for (int i = 0; i < 4; i++)
#pragma unroll
    for (int j = 0; j < 2; j++) acc[i][j] = fz;

#define STAGE_(buf, k0)                                                          \
  {                                                                              \
    GLOAD16(&A[(size_t)(mBase + srow) * D_ + (k0) + ca * 8],                     \
            &As[(buf) * (128 * 32) + (w * 16) * 32]);                            \
    GLOAD16(&Bw[(size_t)(nBase + srow) * D_ + (k0) + ca * 8],                    \
            &Bs[(buf) * (128 * 32) + (w * 16) * 32]);                            \
  }

  STAGE_(0, 0);                              // 2 loads in flight
  int cur = 0;
  for (int t = 0; t < NT; ++t) {
    if (t + 1 < NT) {
      STAGE_(cur ^ 1, (t + 1) * 32);         // 4 in flight
      WAITVM(2);                             // tile t's 2 done; t+1's in flight
    } else {
      WAITVM(0);
    }
    BARRIER();                               // all waves: tile t staged
    s16x8 af[4], bf[2];
#pragma unroll
    for (int mi = 0; mi < 4; mi++) {
      int row = wr * 64 + mi * 16 + lr;
      af[mi] = *(const s16x8*)&As[cur * (128 * 32) + row * 32 + ((lk ^ ((row >> 1) & 3)) << 3)];
    }
#pragma unroll
    for (int ni = 0; ni < 2; ni++) {
      int row = wc * 32 + ni * 16 + lr;
      bf[ni] = *(const s16x8*)&Bs[cur * (128 * 32) + row * 32 + ((lk ^ ((row >> 1) & 3)) << 3)];
    }
#pragma unroll
    for (int mi = 0; mi < 4; mi++)
#pragma unroll
      for (int ni = 0; ni < 2; ni++)
        acc[mi][ni] = __builtin_amdgcn_mfma_f32_16x16x32_bf16(af[mi], bf[ni], acc[mi][ni], 0, 0, 0);
    BARRIER();   // all waves' reads of buf[cur] latched -> safe to re-stage it
    cur ^= 1;
  }
#undef STAGE_

  const float alpha = (z == 0) ? 0.125f * LOG2E : 1.0f;   // Q: 1/sqrt(HD) * log2(e)
#pragma unroll
  for (int mi = 0; mi < 4; mi++)
#pragma unroll
    for (int ni = 0; ni < 2; ni++)
#pragma unroll
      for (int r = 0; r < 4; r++) {
        int gr = mBase + wr * 64 + mi * 16 + lk * 4 + r;
        int gc = nBase + wc * 32 + ni * 16 + lr;
        float v = (acc[mi][ni][r] + bias[gc]) * alpha;
        if (z == 2) {        // V^T: [b][h][d][key]
          int s = gr - bb * S_;
          int hI = gc >> 6, dd = gc & 63;
          Vt[((size_t)(bb * H_ + hI) * HD_ + dd) * SKM + s] = f2bf(v);
        } else if (z == 1) { // K rows with per-batch mem-row gap
          int orow = gr + bb * M_;
          Kb[(size_t)orow * D_ + gc] = f2bf(v);
        } else {
          Qb[(size_t)gr * D_ + gc] = f2bf(v);
        }
      }
}

// ---- gemm_o: R18 BK=64 core (its best measured). 128x128 tile, 8 waves, -----
// 2 buffers, two barriers per K-step, counted WAITVM(4). LDS 64 KB.
// Swizzle (8 chunks): LDS[r][c] = global[r][c ^ (r&7)].
__global__ __launch_bounds__(512)
void gemm_o(const unsigned short* __restrict__ A, const unsigned short* __restrict__ Bw,
            const float* __restrict__ bias, float* __restrict__ Cout) {
  __shared__ __align__(16) unsigned short As[2 * 128 * 64];
  __shared__ __align__(16) unsigned short Bs[2 * 128 * 64];
  const int local = blockIdx.x & 255;
  const int wsz = (local & 7) * 32 + (local >> 3);
  const int nBase = (wsz & 7) * 128, mBase = (wsz >> 3) * 128;
  const int tid = threadIdx.x, lane = tid & 63;
  const int w = tid >> 6, wr = w >> 2, wc = w & 3;
  const int lr = lane & 15, lk = lane >> 4;
  const int rg = lane >> 3;                         // row-in-8 (0..7)
  const int sr0 = w * 8 + rg;                       // staging rows sr0, sr0+64
  const int ca = (lane & 7) ^ (rg & 7);             // inverse-swizzled src chunk
  const int NT = D_ / 64;                           // 16

  const f32x4 fz = {0.f, 0.f, 0.f, 0.f};
  f32x4 acc[4][2];
#pragma unroll
  for (int i = 0; i < 4; i++)
#pragma unroll
    for (int j = 0; j < 2; j++) acc[i][j] = fz;

#define STAGE_(buf, k0)                                                          \
  {                                                                              \
    GLOAD16(&A[(size_t)(mBase + sr0) * D_ + (k0) + ca * 8],                      \
            &As[(buf) * (128 * 64) + (w * 8) * 64]);                             \
    GLOAD16(&A[(size_t)(mBase + 64 + sr0) * D_ + (k0) + ca * 8],                 \
            &As[(buf) * (128 * 64) + (64 + w * 8) * 64]);                        \
    GLOAD16(&Bw[(size_t)(nBase + sr0) * D_ + (k0) + ca * 8],                     \
            &Bs[(buf) * (128 * 64) + (w * 8) * 64]);                             \
    GLOAD16(&Bw[(size_t)(nBase + 64 + sr0) * D_ + (k0) + ca * 8],                \
            &Bs[(buf) * (128 * 64) + (64 + w * 8) * 64]);                        \
  }

  STAGE_(0, 0);                              // 4 loads in flight
  int cur = 0;
  for (int t = 0; t < NT; ++t) {
    if (t + 1 < NT) {
      STAGE_(cur ^ 1, (t + 1) * 64);         // 8 in flight
      WAITVM(4);                             // tile t's 4 done; t+1's in flight
    } else {
      WAITVM(0);
    }
    BARRIER();                               // all waves: tile t staged
#pragma unroll
    for (int ks = 0; ks < 2; ks++) {
      s16x8 af[4], bf[2];
#pragma unroll
      for (int mi = 0; mi < 4; mi++) {
        int row = wr * 64 + mi * 16 + lr;
        af[mi] = *(const s16x8*)&As[cur * (128 * 64) + row * 64 + (((ks * 4 + lk) ^ (row & 7)) << 3)];
      }
#pragma unroll
      for (int ni = 0; ni < 2; ni++) {
        int row = wc * 32 + ni * 16 + lr;
        bf[ni] = *(const s16x8*)&Bs[cur * (128 * 64) + row * 64 + (((ks * 4 + lk) ^ (row & 7)) << 3)];
      }
#pragma unroll
      for (int mi = 0; mi < 4; mi++)
#pragma unroll
        for (int ni = 0; ni < 2; ni++)
          acc[mi][ni] = __builtin_amdgcn_mfma_f32_16x16x32_bf16(af[mi], bf[ni], acc[mi][ni], 0, 0, 0);
    }
    BARRIER();   // all waves' reads of buf[cur] latched -> safe to re-stage it
    cur ^= 1;
  }
#undef STAGE_

#pragma unroll
  for (int mi = 0; mi < 4; mi++)
#pragma unroll
    for (int ni = 0; ni < 2; ni++)
#pragma unroll
      for (int r = 0; r < 4; r++) {
        int gr = mBase + wr * 64 + mi * 16 + lk * 4 + r;
        int gc = nBase + wc * 32 + ni * 16 + lr;
        Cout[(size_t)gr * D_ + gc] = acc[mi][ni][r] + bias[gc];
      }
}

// -------- Flash attention: PAIRED 64-key sub-tiles, ONE barrier per 128 keys --
// (R19 version.) Block: 256 q-rows (8 waves x 32) for one (b,h).
__global__ __launch_bounds__(512)
void attn_kernel(const unsigned short* __restrict__ Qb,
                 const unsigned short* __restrict__ Kb,
                 const unsigned short* __restrict__ VtG,
                 const int* __restrict__ cnt,
                 unsigned short* __restrict__ Xb) {
  __shared__ __align__(16) unsigned short Ks[2 * 2 * 64 * 64];   // [buf][sub][key][d]
  __shared__ __align__(16) unsigned short Vs[2 * 2 * 64 * 64];   // [buf][sub][d][key]

  const int tid = threadIdx.x, lane = tid & 63, w = tid >> 6;   // w: 0..7
  const int l31 = lane & 31, hh = lane >> 5;
  const int qt = blockIdx.x, h = blockIdx.y, b = blockIdx.z;

  const int total = cnt[b] + M_;            // live keys incl. memory slots
  const int nt = (total + 63) >> 6;         // 64-key tiles (<= 33)
  const int npair = (nt + 1) >> 1;

  const int r0 = tid >> 3, c0 = tid & 7;          // staging: row 0..63, chunk 0..7
  const int ck = c0 ^ (r0 & 7);                   // swizzled chunk
  const unsigned short* Kg = Kb + (size_t)b * SKM * D_ + (size_t)h * HD_;
  const unsigned short* Vg = VtG + (size_t)(b * H_ + h) * HD_ * SKM;

  // Q fragments (B-operand of swapped QK^T): Q[q][ds*16 + hh*8 + i]
  const unsigned short* qp = Qb + ((size_t)(b * S_) + qt * 256 + w * 32 + l31) * D_ + h * HD_;
  s16x8 qf[4];
#pragma unroll
  for (int ds = 0; ds < 4; ds++) qf[ds] = *(const s16x8*)&qp[ds * 16 + hh * 8];

  f32x16 accO[2];
#pragma unroll
  for (int dt = 0; dt < 2; dt++)
#pragma unroll
    for (int j = 0; j < 16; j++) accO[dt][j] = 0.f;
  float m_r = -1e20f, l_r = 0.f;

  uint4 kr0, kr1, vr0, vr1;
  auto LOAD = [&](int pair) {   // tiles 2p, 2p+1 clamped to nt-1 (dup masked)
    int t0 = pair * 2;     if (t0 > nt - 1) t0 = nt - 1;
    int t1 = pair * 2 + 1; if (t1 > nt - 1) t1 = nt - 1;
    kr0 = *(const uint4*)&Kg[(size_t)(t0 * 64 + r0) * D_ + c0 * 8];
    kr1 = *(const uint4*)&Kg[(size_t)(t1 * 64 + r0) * D_ + c0 * 8];
    vr0 = *(const uint4*)&Vg[(size_t)r0 * SKM + t0 * 64 + c0 * 8];
    vr1 = *(const uint4*)&Vg[(size_t)r0 * SKM + t1 * 64 + c0 * 8];
  };

  LOAD(0);
  *(uint4*)&Ks[r0 * 64 + ck * 8] = kr0;
  *(uint4*)&Ks[4096 + r0 * 64 + ck * 8] = kr1;
  *(uint4*)&Vs[r0 * 64 + ck * 8] = vr0;
  *(uint4*)&Vs[4096 + r0 * 64 + ck * 8] = vr1;
  __syncthreads();
  int cur = 0;

  for (int p = 0; p < npair; ++p) {
    const bool pre = (p + 1 < npair);
    if (pre) LOAD(p + 1);            // issue-early: lands during compute below

#pragma unroll
    for (int s = 0; s < 2; s++) {
      const int kt = p * 2 + s;
      if (kt >= nt) break;           // uniform (nt is block-uniform)
      const unsigned short* Kc = &Ks[cur * 8192 + s * 4096];
      const unsigned short* Vc = &Vs[cur * 8192 + s * 4096];

      // ---- S^T = K · Q^T : p0 = keys 0..31, p1 = keys 32..63 (q = l31) ----
      f32x16 p0, p1;
#pragma unroll
      for (int j = 0; j < 16; j++) { p0[j] = 0.f; p1[j] = 0.f; }
      __builtin_amdgcn_s_setprio(1);
#pragma unroll
      for (int ds = 0; ds < 4; ds++) {
        s16x8 ka0 = *(const s16x8*)&Kc[l31 * 64 + (((ds * 2 + hh) ^ (l31 & 7)) << 3)];
        s16x8 ka1 = *(const s16x8*)&Kc[(32 + l31) * 64 + (((ds * 2 + hh) ^ (l31 & 7)) << 3)];
        p0 = __builtin_amdgcn_mfma_f32_32x32x16_bf16(ka0, qf[ds], p0, 0, 0, 0);
        p1 = __builtin_amdgcn_mfma_f32_32x32x16_bf16(ka1, qf[ds], p1, 0, 0, 0);
      }
      __builtin_amdgcn_s_setprio(0);

      // ---- tail tile: kill keys beyond `total` (key = (j&3)+8*(j>>2)+4*hh) --
      if (kt == nt - 1) {
        int valid = total - kt * 64;   // 1..64
#pragma unroll
        for (int j = 0; j < 16; j++) {
          int kl = (j & 3) + 8 * (j >> 2) + 4 * hh;
          if (kl >= valid) p0[j] = -1e30f;
          if (kl + 32 >= valid) p1[j] = -1e30f;
        }
      }

      // ---- online softmax in log2 units, defer-max (T13, THR=8) ----
      float vmax = fmaxf(p0[0], p1[0]);
#pragma unroll
      for (int j = 1; j < 16; j++) vmax = fmaxf(vmax, fmaxf(p0[j], p1[j]));
      vmax = fmaxf(vmax, __shfl_xor(vmax, 32));
      if (!__all(vmax - m_r <= 8.0f)) {
        float mnew = fmaxf(m_r, vmax);
        float fac = __builtin_amdgcn_exp2f(m_r - mnew);
        m_r = mnew;
        l_r *= fac;
#pragma unroll
        for (int dt = 0; dt < 2; dt++)
#pragma unroll
          for (int j = 0; j < 16; j++) accO[dt][j] *= fac;
      }
      float sum = 0.f;
#pragma unroll
      for (int j = 0; j < 16; j++) {
        p0[j] = __builtin_amdgcn_exp2f(p0[j] - m_r); sum += p0[j];
        p1[j] = __builtin_amdgcn_exp2f(p1[j] - m_r); sum += p1[j];
      }
      sum += __shfl_xor(sum, 32);
      l_r += sum;

      // ---- build P^T fragments: frag[ks] = P[q][16ks + hh*8 + 0..7] ----
      s16x8 pf_[4];
#pragma unroll
      for (int ks = 0; ks < 4; ks++) {
        const int base = (ks & 1) * 8;
#define ELT(t) ((ks >= 2) ? p1[base + (t)] : p0[base + (t)])
        unsigned w0 = pkbf(ELT(0), ELT(1));
        unsigned w1 = pkbf(ELT(2), ELT(3));
        unsigned w2 = pkbf(ELT(4), ELT(5));
        unsigned w3 = pkbf(ELT(6), ELT(7));
#undef ELT
        unsigned s0 = hh ? w0 : w2;       // h0 sends keys {8..11}, h1 sends {4..7}
        unsigned s1 = hh ? w1 : w3;
        unsigned g0 = (unsigned)__shfl_xor((int)s0, 32);
        unsigned g1 = (unsigned)__shfl_xor((int)s1, 32);
        union { s16x8 v; unsigned u[4]; } pf;
        pf.u[0] = hh ? g0 : w0;
        pf.u[1] = hh ? g1 : w1;
        pf.u[2] = hh ? w2 : g0;
        pf.u[3] = hh ? w3 : g1;
        pf_[ks] = pf.v;
      }

      // ---- O^T += V^T · P^T  (row d = dt*32+(j&3)+8*(j>>2)+4*hh, q = l31) ---
      __builtin_amdgcn_s_setprio(1);
#pragma unroll
      for (int dt = 0; dt < 2; dt++)
#pragma unroll
        for (int ks = 0; ks < 4; ks++) {
          s16x8 va = *(const s16x8*)&Vc[(dt * 32 + l31) * 64 + (((ks * 2 + hh) ^ (l31 & 7)) << 3)];
          accO[dt] = __builtin_amdgcn_mfma_f32_32x32x16_bf16(va, pf_[ks], accO[dt], 0, 0, 0);
        }
      __builtin_amdgcn_s_setprio(0);
    }

    // ---- write-late: stage pair p+1 into buf^1 (no reader this iter) --------
    if (pre) {
      int ob = (cur ^ 1) * 8192;
      *(uint4*)&Ks[ob + r0 * 64 + ck * 8] = kr0;
      *(uint4*)&Ks[ob + 4096 + r0 * 64 + ck * 8] = kr1;
      *(uint4*)&Vs[ob + r0 * 64 + ck * 8] = vr0;
      *(uint4*)&Vs[ob + 4096 + r0 * 64 + ck * 8] = vr1;
      __syncthreads();               // ONE barrier per 128 keys
      cur ^= 1;
    }
  }

  float invl = 1.0f / l_r;
  size_t orow = ((size_t)(b * S_) + qt * 256 + w * 32 + l31) * D_ + h * HD_;
#pragma unroll
  for (int dt = 0; dt < 2; dt++)
#pragma unroll
    for (int j = 0; j < 16; j++) {
      int d = dt * 32 + (j & 3) + 8 * (j >> 2) + 4 * hh;
      Xb[orow + d] = f2bf(accO[dt][j] * invl);
    }
}

// ------------------------------- launcher -------------------------------------
extern "C" void kernel_launch(void* const* d_in, const int* in_sizes, int n_in,
                              void* d_out, int out_size, void* d_ws, size_t ws_size,
                              hipStream_t stream) {
  const float* query = (const float*)d_in[0];
  const float* key   = (const float*)d_in[1];
  const float* value = (const float*)d_in[2];
  const int*   mask  = (const int*)d_in[3];
  const float* Wq    = (const float*)d_in[4];
  const float* bq    = (const float*)d_in[5];
  const float* Wk    = (const float*)d_in[6];
  const float* bk    = (const float*)d_in[7];
  const float* Wv    = (const float*)d_in[8];
  const float* bv    = (const float*)d_in[9];
  const float* Wo    = (const float*)d_in[10];
  const float* bo    = (const float*)d_in[11];
  const float* m_k   = (const float*)d_in[12];
  const float* m_v   = (const float*)d_in[13];

  const int NQ = B_ * S_ * D_;     // 4,194,304
  const int NW = D_ * D_;          // 1,048,576 = 2^20
  const int NK = B_ * SKM * D_;    // 4,325,376

  unsigned short* ws = (unsigned short*)d_ws;   // ~67.6 MB + 16 KB
  unsigned short* qf = ws;
  unsigned short* kf = qf + NQ;
  unsigned short* vf = kf + NQ;
  unsigned short* wq = vf + NQ;
  unsigned short* wk = wq + NW;
  unsigned short* wv = wk + NW;
  unsigned short* wo = wv + NW;
  unsigned short* Qb = wo + NW;
  unsigned short* Kb = Qb + NQ;
  unsigned short* Vt = Kb + NK;    // [b][h][d][key]
  unsigned short* Xb = Vt + NK;
  int* idx = (int*)(Xb + NQ);      // [B][S]
  int* cnt = idx + B_ * S_;        // [B]

  compact_mask<<<B_, 1024, 0, stream>>>(mask, idx, cnt);
  // one launch: query+weights linear cvt (8192 blocks) + K/V gather (8192)
  cvt_fused<<<16384, 256, 0, stream>>>(query, Wq, Wk, Wv, Wo, key, value,
                                       qf, wq, wk, wv, wo, kf, vf, idx, cnt);

  // merged Q/K/V projection, BK=32 core (its best measured config)
  gemm_qkv<<<768, 512, 0, stream>>>(qf, kf, vf, wq, wk, wv, bq, bk, bv, Qb, Kb, Vt, cnt);
  // memory rows appended at key position cnt[b] — must run AFTER K/V GEMMs
  fill_mem<<<(M_ * D_) / 256, 256, 0, stream>>>(m_k, m_v, Kb, Vt, cnt);

  attn_kernel<<<dim3(S_ / 256, H_, B_), 512, 0, stream>>>(Qb, Kb, Vt, cnt, Xb);

  // output projection, BK=64 core (its best measured config)
  gemm_o<<<256, 512, 0, stream>>>(Xb, wo, bo, (float*)d_out);
}

// Round 21
// 119.721 us; speedup vs baseline: 1.0747x; 1.0130x over previous
//
#include <hip/hip_runtime.h>
#include <hip/hip_bf16.h>
#include <stdint.h>

// Problem constants (B,S,D,H,M) = (2,2048,1024,16,64), HD=64
#define B_  2
#define S_  2048
#define D_  1024
#define H_  16
#define HD_ 64
#define M_  64
#define SKM (S_ + M_)   // 2112
#define LOG2E 1.44269504088896340736f

typedef __attribute__((ext_vector_type(8))) short s16x8;
typedef __attribute__((ext_vector_type(4))) float f32x4;
typedef __attribute__((ext_vector_type(16))) float f32x16;

// global_load_lds width=16: linear LDS dest (base + lane*16), per-lane global src
#define GLOAD16(gp, lp) __builtin_amdgcn_global_load_lds( \
    (const __attribute__((address_space(1))) void*)(gp),  \
    (__attribute__((address_space(3))) void*)(lp), 16, 0, 0)

// counted vmcnt wait (T4): literal N, then pin scheduler (rule #18)
#define WAITVM(N) do { asm volatile("s_waitcnt vmcnt(" #N ")" ::: "memory"); \
                       __builtin_amdgcn_sched_barrier(0); } while (0)
// raw s_barrier WITHOUT the __syncthreads vmcnt(0) drain
#define BARRIER() do { asm volatile("" ::: "memory"); \
                       __builtin_amdgcn_s_barrier(); \
                       asm volatile("" ::: "memory"); } while (0)

__device__ __forceinline__ unsigned short f2bf(float f) {
  union { float f; unsigned int u; } v; v.f = f;
  unsigned int r = v.u + 0x7fffu + ((v.u >> 16) & 1u);  // RNE
  return (unsigned short)(r >> 16);
}

__device__ __forceinline__ unsigned pkbf(float lo, float hi) {
  union { __hip_bfloat162 b; unsigned u; } t;
  t.b = __float22bfloat162_rn(make_float2(lo, hi));   // -> v_cvt_pk_bf16_f32
  return t.u;
}

// ---- mask compaction: idx[b][j] = j-th unmasked key, cnt[b] = count ----------
__global__ void compact_mask(const int* __restrict__ mask,
                             int* __restrict__ idx, int* __restrict__ cnt) {
  const int b = blockIdx.x;
  __shared__ int base, wsum[16];
  if (threadIdx.x == 0) base = 0;
  const int lane = threadIdx.x & 63, w = threadIdx.x >> 6;   // w: 0..15
  __syncthreads();
  for (int c = 0; c < S_; c += 1024) {
    int key = c + threadIdx.x;
    int mv = mask[b * S_ + key];
    unsigned long long bal = __ballot(mv != 0);
    int pre = __popcll(bal & ((1ull << lane) - 1ull));
    if (lane == 0) wsum[w] = __popcll(bal);
    __syncthreads();
    int woff = 0;
#pragma unroll
    for (int i = 0; i < 16; i++) woff += (i < w) ? wsum[i] : 0;
    int tot = 0;
#pragma unroll
    for (int i = 0; i < 16; i++) tot += wsum[i];
    if (mv) idx[b * S_ + base + woff + pre] = key;
    __syncthreads();
    if (threadIdx.x == 0) base += tot;
    __syncthreads();
  }
  if (threadIdx.x == 0) cnt[b] = base;
}

// ---- ALL conversions in ONE launch: query + weights + K/V gather + mem fill --
// bid <  8192 : linear cvt of [query | Wq | Wk | Wv | Wo]
// bid < 16384 : gather-convert one key/value row through idx (mask=1 rows only)
// bid >=16384 : mem rows K_mem=8*m_k, V_mem=8*m_v at FIXED key offset S_
//               (region never touched by the GEMMs -> order-free)
__global__ void cvt_fused(const float* __restrict__ q,
                          const float* __restrict__ w0, const float* __restrict__ w1,
                          const float* __restrict__ w2, const float* __restrict__ w3,
                          const float* __restrict__ key, const float* __restrict__ value,
                          const float* __restrict__ mk, const float* __restrict__ mv,
                          unsigned short* __restrict__ qf,
                          unsigned short* __restrict__ o0, unsigned short* __restrict__ o1,
                          unsigned short* __restrict__ o2, unsigned short* __restrict__ o3,
                          unsigned short* __restrict__ kf, unsigned short* __restrict__ vf,
                          unsigned short* __restrict__ Kb, unsigned short* __restrict__ Vt,
                          const int* __restrict__ idx, const int* __restrict__ cnt) {
  const size_t NQs = (size_t)B_ * S_ * D_;
  if (blockIdx.x < 8192) {
    size_t i = ((size_t)blockIdx.x * 256 + threadIdx.x) * 4;
    const float* in; unsigned short* out; size_t off;
    if (i < NQs) { in = q; out = qf; off = i; }
    else {
      size_t j = i - NQs;
      int wsel = (int)(j >> 20);
      off = j & ((1u << 20) - 1);
      in  = (wsel == 0) ? w0 : (wsel == 1) ? w1 : (wsel == 2) ? w2 : w3;
      out = (wsel == 0) ? o0 : (wsel == 1) ? o1 : (wsel == 2) ? o2 : o3;
    }
    float4 v = *(const float4*)&in[off];
    ushort4 o;
    o.x = f2bf(v.x); o.y = f2bf(v.y); o.z = f2bf(v.z); o.w = f2bf(v.w);
    *(ushort4*)&out[off] = o;
  } else if (blockIdx.x < 16384) {
    int gid = blockIdx.x - 8192;         // [0, 8192)
    int kv = gid >> 12, rem = gid & 4095;
    int b = rem >> 11, j = rem & 2047;
    if (j >= cnt[b]) return;
    const float* in = kv ? value : key;
    unsigned short* out = kv ? vf : kf;
    int src = idx[b * S_ + j];
    const float* ip = in + ((size_t)(b * S_) + src) * D_;
    unsigned short* op = out + ((size_t)(b * S_) + j) * D_;
    int t = threadIdx.x * 4;
    float4 v = *(const float4*)&ip[t];
    ushort4 o;
    o.x = f2bf(v.x); o.y = f2bf(v.y); o.z = f2bf(v.z); o.w = f2bf(v.w);
    *(ushort4*)&op[t] = o;
  } else {
    // mem fill: 64 blocks x 256 threads x 4 elems = M_*D_ = 65536
    int i = (blockIdx.x - 16384) * 1024 + threadIdx.x * 4;
    int row = i >> 10, col = i & 1023;       // col aligned to 4, same head
    int hI = col >> 6, dd = col & 63;
    float4 a = *(const float4*)&mk[i];
    float4 v = *(const float4*)&mv[i];
    ushort4 ko;
    ko.x = f2bf(8.0f * a.x); ko.y = f2bf(8.0f * a.y);
    ko.z = f2bf(8.0f * a.z); ko.w = f2bf(8.0f * a.w);
    unsigned short vo0 = f2bf(8.0f * v.x), vo1 = f2bf(8.0f * v.y);
    unsigned short vo2 = f2bf(8.0f * v.z), vo3 = f2bf(8.0f * v.w);
#pragma unroll
    for (int b = 0; b < B_; b++) {
      *(ushort4*)&Kb[((size_t)(b * SKM) + S_ + row) * D_ + col] = ko;
      size_t vb = ((size_t)(b * H_ + hI) * HD_ + dd) * SKM + S_ + row;
      Vt[vb] = vo0;
      Vt[vb + SKM] = vo1;
      Vt[vb + 2 * SKM] = vo2;
      Vt[vb + 3 * SKM] = vo3;
    }
  }
}

// ------ gemm_qkv: BK=32 core (best measured 44.6 us tight). -------------------
// 128x128 tile, 8 waves (64x32/wave), 2 buffers, TWO barriers per K-step,
// counted WAITVM(2). LDS 32 KB. Swizzle: LDS[r][c] = global[r][c^((r>>1)&3)].
__global__ __launch_bounds__(512)
void gemm_qkv(const unsigned short* __restrict__ qf, const unsigned short* __restrict__ kf,
              const unsigned short* __restrict__ vf,
              const unsigned short* __restrict__ wq, const unsigned short* __restrict__ wk,
              const unsigned short* __restrict__ wv,
              const float* __restrict__ bq, const float* __restrict__ bk,
              const float* __restrict__ bv,
              unsigned short* __restrict__ Qb, unsigned short* __restrict__ Kb,
              unsigned short* __restrict__ Vt,
              const int* __restrict__ cnt) {
  __shared__ __align__(16) unsigned short As[2 * 128 * 32];
  __shared__ __align__(16) unsigned short Bs[2 * 128 * 32];
  // T1: within each z-slice of 256 works, XCD (bid&7) owns 32 contiguous works
  const int z = blockIdx.x >> 8;
  const int local = blockIdx.x & 255;
  const int wsz = (local & 7) * 32 + (local >> 3);   // bijective (256 = 8*32)
  const int nBase = (wsz & 7) * 128, mBase = (wsz >> 3) * 128;
  const int bb = (mBase >= S_);
  if (z) {   // K/V: skip tiles entirely beyond the compacted row count
    if (mBase - bb * S_ >= cnt[bb]) return;
  }
  const unsigned short* A  = (z == 0) ? qf : (z == 1) ? kf : vf;
  const unsigned short* Bw = (z == 0) ? wq : (z == 1) ? wk : wv;
  const float* bias        = (z == 0) ? bq : (z == 1) ? bk : bv;

  const int tid = threadIdx.x, lane = tid & 63;
  const int w = tid >> 6;                  // 0..7
  const int wr = w >> 2, wc = w & 3;       // 2x4 wave grid, 64x32 per wave
  const int lr = lane & 15, lk = lane >> 4;
  const int srow = tid >> 2;               // staging row 0..127
  const int cd = tid & 3;                  // dest chunk (linear)
  const int ca = cd ^ ((srow >> 1) & 3);   // inverse-swizzled source chunk
  const int NT = D_ / 32;                  // 32

  const f32x4 fz = {0.f, 0.f, 0.f, 0.f};
  f32x4 acc[4][2];
#pragma unroll
  for (int i = 0; i < 4; i++)
#pragma unroll
    for (int j = 0; j < 2; j++) acc[i][j] = fz;

#define STAGE_(buf, k0)                                                          \
  {                                                                              \
    GLOAD16(&A[(size_t)(mBase + srow) * D_ + (k0) + ca * 8],                     \
            &As[(buf) * (128 * 32) + (w * 16) * 32]);                            \
    GLOAD16(&Bw[(size_t)(nBase + srow) * D_ + (k0) + ca * 8],                    \
            &Bs[(buf) * (128 * 32) + (w * 16) * 32]);                            \
  }

  STAGE_(0, 0);                              // 2 loads in flight
  int cur = 0;
  for (int t = 0; t < NT; ++t) {
    if (t + 1 < NT) {
      STAGE_(cur ^ 1, (t + 1) * 32);         // 4 in flight
      WAITVM(2);                             // tile t's 2 done; t+1's in flight
    } else {
      WAITVM(0);
    }
    BARRIER();                               // all waves: tile t staged
    s16x8 af[4], bf[2];
#pragma unroll
    for (int mi = 0; mi < 4; mi++) {
      int row = wr * 64 + mi * 16 + lr;
      af[mi] = *(const s16x8*)&As[cur * (128 * 32) + row * 32 + ((lk ^ ((row >> 1) & 3)) << 3)];
    }
#pragma unroll
    for (int ni = 0; ni < 2; ni++) {
      int row = wc * 32 + ni * 16 + lr;
      bf[ni] = *(const s16x8*)&Bs[cur * (128 * 32) + row * 32 + ((lk ^ ((row >> 1) & 3)) << 3)];
    }
#pragma unroll
    for (int mi = 0; mi < 4; mi++)
#pragma unroll
      for (int ni = 0; ni < 2; ni++)
        acc[mi][ni] = __builtin_amdgcn_mfma_f32_16x16x32_bf16(af[mi], bf[ni], acc[mi][ni], 0, 0, 0);
    BARRIER();   // all waves' reads of buf[cur] latched -> safe to re-stage it
    cur ^= 1;
  }
#undef STAGE_

  const float alpha = (z == 0) ? 0.125f * LOG2E : 1.0f;   // Q: 1/sqrt(HD) * log2(e)
#pragma unroll
  for (int mi = 0; mi < 4; mi++)
#pragma unroll
    for (int ni = 0; ni < 2; ni++)
#pragma unroll
      for (int r = 0; r < 4; r++) {
        int gr = mBase + wr * 64 + mi * 16 + lk * 4 + r;
        int gc = nBase + wc * 32 + ni * 16 + lr;
        float v = (acc[mi][ni][r] + bias[gc]) * alpha;
        if (z == 2) {        // V^T: [b][h][d][key]; keys [0,S_) only
          int s = gr - bb * S_;
          int hI = gc >> 6, dd = gc & 63;
          Vt[((size_t)(bb * H_ + hI) * HD_ + dd) * SKM + s] = f2bf(v);
        } else if (z == 1) { // K rows [0,S_) with per-batch 64-row mem gap
          int orow = gr + bb * M_;
          Kb[(size_t)orow * D_ + gc] = f2bf(v);
        } else {
          Qb[(size_t)gr * D_ + gc] = f2bf(v);
        }
      }
}

// ---- gemm_o: BK=64 core (its best measured). 128x128 tile, 8 waves, ---------
// 2 buffers, two barriers per K-step, counted WAITVM(4). LDS 64 KB.
// Swizzle (8 chunks): LDS[r][c] = global[r][c ^ (r&7)].
__global__ __launch_bounds__(512)
void gemm_o(const unsigned short* __restrict__ A, const unsigned short* __restrict__ Bw,
            const float* __restrict__ bias, float* __restrict__ Cout) {
  __shared__ __align__(16) unsigned short As[2 * 128 * 64];
  __shared__ __align__(16) unsigned short Bs[2 * 128 * 64];
  const int local = blockIdx.x & 255;
  const int wsz = (local & 7) * 32 + (local >> 3);
  const int nBase = (wsz & 7) * 128, mBase = (wsz >> 3) * 128;
  const int tid = threadIdx.x, lane = tid & 63;
  const int w = tid >> 6, wr = w >> 2, wc = w & 3;
  const int lr = lane & 15, lk = lane >> 4;
  const int rg = lane >> 3;                         // row-in-8 (0..7)
  const int sr0 = w * 8 + rg;                       // staging rows sr0, sr0+64
  const int ca = (lane & 7) ^ (rg & 7);             // inverse-swizzled src chunk
  const int NT = D_ / 64;                           // 16

  const f32x4 fz = {0.f, 0.f, 0.f, 0.f};
  f32x4 acc[4][2];
#pragma unroll
  for (int i = 0; i < 4; i++)
#pragma unroll
    for (int j = 0; j < 2; j++) acc[i][j] = fz;

#define STAGE_(buf, k0)                                                          \
  {                                                                              \
    GLOAD16(&A[(size_t)(mBase + sr0) * D_ + (k0) + ca * 8],                      \
            &As[(buf) * (128 * 64) + (w * 8) * 64]);                             \
    GLOAD16(&A[(size_t)(mBase + 64 + sr0) * D_ + (k0) + ca * 8],                 \
            &As[(buf) * (128 * 64) + (64 + w * 8) * 64]);                        \
    GLOAD16(&Bw[(size_t)(nBase + sr0) * D_ + (k0) + ca * 8],                     \
            &Bs[(buf) * (128 * 64) + (w * 8) * 64]);                             \
    GLOAD16(&Bw[(size_t)(nBase + 64 + sr0) * D_ + (k0) + ca * 8],                \
            &Bs[(buf) * (128 * 64) + (64 + w * 8) * 64]);                        \
  }

  STAGE_(0, 0);                              // 4 loads in flight
  int cur = 0;
  for (int t = 0; t < NT; ++t) {
    if (t + 1 < NT) {
      STAGE_(cur ^ 1, (t + 1) * 64);         // 8 in flight
      WAITVM(4);                             // tile t's 4 done; t+1's in flight
    } else {
      WAITVM(0);
    }
    BARRIER();                               // all waves: tile t staged
#pragma unroll
    for (int ks = 0; ks < 2; ks++) {
      s16x8 af[4], bf[2];
#pragma unroll
      for (int mi = 0; mi < 4; mi++) {
        int row = wr * 64 + mi * 16 + lr;
        af[mi] = *(const s16x8*)&As[cur * (128 * 64) + row * 64 + (((ks * 4 + lk) ^ (row & 7)) << 3)];
      }
#pragma unroll
      for (int ni = 0; ni < 2; ni++) {
        int row = wc * 32 + ni * 16 + lr;
        bf[ni] = *(const s16x8*)&Bs[cur * (128 * 64) + row * 64 + (((ks * 4 + lk) ^ (row & 7)) << 3)];
      }
#pragma unroll
      for (int mi = 0; mi < 4; mi++)
#pragma unroll
        for (int ni = 0; ni < 2; ni++)
          acc[mi][ni] = __builtin_amdgcn_mfma_f32_16x16x32_bf16(af[mi], bf[ni], acc[mi][ni], 0, 0, 0);
    }
    BARRIER();   // all waves' reads of buf[cur] latched -> safe to re-stage it
    cur ^= 1;
  }
#undef STAGE_

#pragma unroll
  for (int mi = 0; mi < 4; mi++)
#pragma unroll
    for (int ni = 0; ni < 2; ni++)
#pragma unroll
      for (int r = 0; r < 4; r++) {
        int gr = mBase + wr * 64 + mi * 16 + lk * 4 + r;
        int gc = nBase + wc * 32 + ni * 16 + lr;
        Cout[(size_t)gr * D_ + gc] = acc[mi][ni][r] + bias[gc];
      }
}

// -------- Flash attention: PAIRED 64-key sub-tiles, ONE barrier per 128 keys --
// Tiles: nt_live live-key tiles (tail-masked) + ONE fixed mem tile at key
// offset S_ (M_=64 = exactly one full tile). Block: 256 q-rows (8 waves x 32).
__global__ __launch_bounds__(512)
void attn_kernel(const unsigned short* __restrict__ Qb,
                 const unsigned short* __restrict__ Kb,
                 const unsigned short* __restrict__ VtG,
                 const int* __restrict__ cnt,
                 unsigned short* __restrict__ Xb) {
  __shared__ __align__(16) unsigned short Ks[2 * 2 * 64 * 64];   // [buf][sub][key][d]
  __shared__ __align__(16) unsigned short Vs[2 * 2 * 64 * 64];   // [buf][sub][d][key]

  const int tid = threadIdx.x, lane = tid & 63, w = tid >> 6;   // w: 0..7
  const int l31 = lane & 31, hh = lane >> 5;
  const int qt = blockIdx.x, h = blockIdx.y, b = blockIdx.z;

  const int cb = cnt[b];                    // live keys
  const int nt_live = (cb + 63) >> 6;       // live 64-key tiles
  const int ntot = nt_live + 1;             // + fixed mem tile
  const int npair = (ntot + 1) >> 1;

  const int r0 = tid >> 3, c0 = tid & 7;          // staging: row 0..63, chunk 0..7
  const int ck = c0 ^ (r0 & 7);                   // swizzled chunk
  const unsigned short* Kg = Kb + (size_t)b * SKM * D_ + (size_t)h * HD_;
  const unsigned short* Vg = VtG + (size_t)(b * H_ + h) * HD_ * SKM;

  // Q fragments (B-operand of swapped QK^T): Q[q][ds*16 + hh*8 + i]
  const unsigned short* qp = Qb + ((size_t)(b * S_) + qt * 256 + w * 32 + l31) * D_ + h * HD_;
  s16x8 qf[4];
#pragma unroll
  for (int ds = 0; ds < 4; ds++) qf[ds] = *(const s16x8*)&qp[ds * 16 + hh * 8];

  f32x16 accO[2];
#pragma unroll
  for (int dt = 0; dt < 2; dt++)
#pragma unroll
    for (int j = 0; j < 16; j++) accO[dt][j] = 0.f;
  float m_r = -1e20f, l_r = 0.f;

  // key offset of tile t: live tiles at t*64, mem tile at fixed S_
  auto toff = [&](int t) { return (t < nt_live) ? t * 64 : S_; };

  uint4 kr0, kr1, vr0, vr1;
  auto LOAD = [&](int pair) {   // tiles 2p, 2p+1 clamped to ntot-1 (dup unused)
    int t0 = pair * 2;     if (t0 > ntot - 1) t0 = ntot - 1;
    int t1 = pair * 2 + 1; if (t1 > ntot - 1) t1 = ntot - 1;
    int o0 = toff(t0), o1 = toff(t1);
    kr0 = *(const uint4*)&Kg[(size_t)(o0 + r0) * D_ + c0 * 8];
    kr1 = *(const uint4*)&Kg[(size_t)(o1 + r0) * D_ + c0 * 8];
    vr0 = *(const uint4*)&Vg[(size_t)r0 * SKM + o0 + c0 * 8];
    vr1 = *(const uint4*)&Vg[(size_t)r0 * SKM + o1 + c0 * 8];
  };

  LOAD(0);
  *(uint4*)&Ks[r0 * 64 + ck * 8] = kr0;
  *(uint4*)&Ks[4096 + r0 * 64 + ck * 8] = kr1;
  *(uint4*)&Vs[r0 * 64 + ck * 8] = vr0;
  *(uint4*)&Vs[4096 + r0 * 64 + ck * 8] = vr1;
  __syncthreads();
  int cur = 0;

  for (int p = 0; p < npair; ++p) {
    const bool pre = (p + 1 < npair);
    if (pre) LOAD(p + 1);            // issue-early: lands during compute below

#pragma unroll
    for (int s = 0; s < 2; s++) {
      const int kt = p * 2 + s;
      if (kt >= ntot) break;         // uniform (ntot is block-uniform)
      const unsigned short* Kc = &Ks[cur * 8192 + s * 4096];
      const unsigned short* Vc = &Vs[cur * 8192 + s * 4096];

      // ---- S^T = K · Q^T : p0 = keys 0..31, p1 = keys 32..63 (q = l31) ----
      f32x16 p0, p1;
#pragma unroll
      for (int j = 0; j < 16; j++) { p0[j] = 0.f; p1[j] = 0.f; }
      __builtin_amdgcn_s_setprio(1);
#pragma unroll
      for (int ds = 0; ds < 4; ds++) {
        s16x8 ka0 = *(const s16x8*)&Kc[l31 * 64 + (((ds * 2 + hh) ^ (l31 & 7)) << 3)];
        s16x8 ka1 = *(const s16x8*)&Kc[(32 + l31) * 64 + (((ds * 2 + hh) ^ (l31 & 7)) << 3)];
        p0 = __builtin_amdgcn_mfma_f32_32x32x16_bf16(ka0, qf[ds], p0, 0, 0, 0);
        p1 = __builtin_amdgcn_mfma_f32_32x32x16_bf16(ka1, qf[ds], p1, 0, 0, 0);
      }
      __builtin_amdgcn_s_setprio(0);

      // ---- last LIVE tile: kill keys beyond cb (key = (j&3)+8*(j>>2)+4*hh) --
      if (kt == nt_live - 1) {
        int valid = cb - kt * 64;   // 1..64
#pragma unroll
        for (int j = 0; j < 16; j++) {
          int kl = (j & 3) + 8 * (j >> 2) + 4 * hh;
          if (kl >= valid) p0[j] = -1e30f;
          if (kl + 32 >= valid) p1[j] = -1e30f;
        }
      }

      // ---- online softmax in log2 units, defer-max (T13, THR=8) ----
      float vmax = fmaxf(p0[0], p1[0]);
#pragma unroll
      for (int j = 1; j < 16; j++) vmax = fmaxf(vmax, fmaxf(p0[j], p1[j]));
      vmax = fmaxf(vmax, __shfl_xor(vmax, 32));
      if (!__all(vmax - m_r <= 8.0f)) {
        float mnew = fmaxf(m_r, vmax);
        float fac = __builtin_amdgcn_exp2f(m_r - mnew);
        m_r = mnew;
        l_r *= fac;
#pragma unroll
        for (int dt = 0; dt < 2; dt++)
#pragma unroll
          for (int j = 0; j < 16; j++) accO[dt][j] *= fac;
      }
      float sum = 0.f;
#pragma unroll
      for (int j = 0; j < 16; j++) {
        p0[j] = __builtin_amdgcn_exp2f(p0[j] - m_r); sum += p0[j];
        p1[j] = __builtin_amdgcn_exp2f(p1[j] - m_r); sum += p1[j];
      }
      sum += __shfl_xor(sum, 32);
      l_r += sum;

      // ---- build P^T fragments: frag[ks] = P[q][16ks + hh*8 + 0..7] ----
      s16x8 pf_[4];
#pragma unroll
      for (int ks = 0; ks < 4; ks++) {
        const int base = (ks & 1) * 8;
#define ELT(t) ((ks >= 2) ? p1[base + (t)] : p0[base + (t)])
        unsigned w0 = pkbf(ELT(0), ELT(1));
        unsigned w1 = pkbf(ELT(2), ELT(3));
        unsigned w2 = pkbf(ELT(4), ELT(5));
        unsigned w3 = pkbf(ELT(6), ELT(7));
#undef ELT
        unsigned s0 = hh ? w0 : w2;       // h0 sends keys {8..11}, h1 sends {4..7}
        unsigned s1 = hh ? w1 : w3;
        unsigned g0 = (unsigned)__shfl_xor((int)s0, 32);
        unsigned g1 = (unsigned)__shfl_xor((int)s1, 32);
        union { s16x8 v; unsigned u[4]; } pf;
        pf.u[0] = hh ? g0 : w0;
        pf.u[1] = hh ? g1 : w1;
        pf.u[2] = hh ? w2 : g0;
        pf.u[3] = hh ? w3 : g1;
        pf_[ks] = pf.v;
      }

      // ---- O^T += V^T · P^T  (row d = dt*32+(j&3)+8*(j>>2)+4*hh, q = l31) ---
      __builtin_amdgcn_s_setprio(1);
#pragma unroll
      for (int dt = 0; dt < 2; dt++)
#pragma unroll
        for (int ks = 0; ks < 4; ks++) {
          s16x8 va = *(const s16x8*)&Vc[(dt * 32 + l31) * 64 + (((ks * 2 + hh) ^ (l31 & 7)) << 3)];
          accO[dt] = __builtin_amdgcn_mfma_f32_32x32x16_bf16(va, pf_[ks], accO[dt], 0, 0, 0);
        }
      __builtin_amdgcn_s_setprio(0);
    }

    // ---- write-late: stage pair p+1 into buf^1 (no reader this iter) --------
    if (pre) {
      int ob = (cur ^ 1) * 8192;
      *(uint4*)&Ks[ob + r0 * 64 + ck * 8] = kr0;
      *(uint4*)&Ks[ob + 4096 + r0 * 64 + ck * 8] = kr1;
      *(uint4*)&Vs[ob + r0 * 64 + ck * 8] = vr0;
      *(uint4*)&Vs[ob + 4096 + r0 * 64 + ck * 8] = vr1;
      __syncthreads();               // ONE barrier per 128 keys
      cur ^= 1;
    }
  }

  float invl = 1.0f / l_r;
  size_t orow = ((size_t)(b * S_) + qt * 256 + w * 32 + l31) * D_ + h * HD_;
#pragma unroll
  for (int dt = 0; dt < 2; dt++)
#pragma unroll
    for (int j = 0; j < 16; j++) {
      int d = dt * 32 + (j & 3) + 8 * (j >> 2) + 4 * hh;
      Xb[orow + d] = f2bf(accO[dt][j] * invl);
    }
}

// ------------------------------- launcher -------------------------------------
extern "C" void kernel_launch(void* const* d_in, const int* in_sizes, int n_in,
                              void* d_out, int out_size, void* d_ws, size_t ws_size,
                              hipStream_t stream) {
  const float* query = (const float*)d_in[0];
  const float* key   = (const float*)d_in[1];
  const float* value = (const float*)d_in[2];
  const int*   mask  = (const int*)d_in[3];
  const float* Wq    = (const float*)d_in[4];
  const float* bq    = (const float*)d_in[5];
  const float* Wk    = (const float*)d_in[6];
  const float* bk    = (const float*)d_in[7];
  const float* Wv    = (const float*)d_in[8];
  const float* bv    = (const float*)d_in[9];
  const float* Wo    = (const float*)d_in[10];
  const float* bo    = (const float*)d_in[11];
  const float* m_k   = (const float*)d_in[12];
  const float* m_v   = (const float*)d_in[13];

  const int NQ = B_ * S_ * D_;     // 4,194,304
  const int NW = D_ * D_;          // 1,048,576 = 2^20
  const int NK = B_ * SKM * D_;    // 4,325,376

  unsigned short* ws = (unsigned short*)d_ws;   // ~67.6 MB + 16 KB
  unsigned short* qf = ws;
  unsigned short* kf = qf + NQ;
  unsigned short* vf = kf + NQ;
  unsigned short* wq = vf + NQ;
  unsigned short* wk = wq + NW;
  unsigned short* wv = wk + NW;
  unsigned short* wo = wv + NW;
  unsigned short* Qb = wo + NW;
  unsigned short* Kb = Qb + NQ;
  unsigned short* Vt = Kb + NK;    // [b][h][d][key]
  unsigned short* Xb = Vt + NK;
  int* idx = (int*)(Xb + NQ);      // [B][S]
  int* cnt = idx + B_ * S_;        // [B]

  compact_mask<<<B_, 1024, 0, stream>>>(mask, idx, cnt);
  // one launch: query+weights cvt (8192) + K/V gather (8192) + mem fill (64)
  cvt_fused<<<16448, 256, 0, stream>>>(query, Wq, Wk, Wv, Wo, key, value,
                                       m_k, m_v, qf, wq, wk, wv, wo,
                                       kf, vf, Kb, Vt, idx, cnt);

  // merged Q/K/V projection, BK=32 core (its best measured config)
  gemm_qkv<<<768, 512, 0, stream>>>(qf, kf, vf, wq, wk, wv, bq, bk, bv, Qb, Kb, Vt, cnt);

  attn_kernel<<<dim3(S_ / 256, H_, B_), 512, 0, stream>>>(Qb, Kb, Vt, cnt, Xb);

  // output projection, BK=64 core (its best measured config)
  gemm_o<<<256, 512, 0, stream>>>(Xb, wo, bo, (float*)d_out);
}

// Round 22
// 119.651 us; speedup vs baseline: 1.0753x; 1.0006x over previous
//
#include <hip/hip_runtime.h>
#include <hip/hip_bf16.h>
#include <stdint.h>

// Problem constants (B,S,D,H,M) = (2,2048,1024,16,64), HD=64
#define B_  2
#define S_  2048
#define D_  1024
#define H_  16
#define HD_ 64
#define M_  64
#define SKM (S_ + M_)   // 2112
#define LOG2E 1.44269504088896340736f

typedef __attribute__((ext_vector_type(8))) short s16x8;
typedef __attribute__((ext_vector_type(4))) float f32x4;
typedef __attribute__((ext_vector_type(16))) float f32x16;

// global_load_lds width=16: linear LDS dest (base + lane*16), per-lane global src
#define GLOAD16(gp, lp) __builtin_amdgcn_global_load_lds( \
    (const __attribute__((address_space(1))) void*)(gp),  \
    (__attribute__((address_space(3))) void*)(lp), 16, 0, 0)

// counted vmcnt wait (T4): literal N, then pin scheduler (rule #18)
#define WAITVM(N) do { asm volatile("s_waitcnt vmcnt(" #N ")" ::: "memory"); \
                       __builtin_amdgcn_sched_barrier(0); } while (0)
// raw s_barrier WITHOUT the __syncthreads vmcnt(0) drain
#define BARRIER() do { asm volatile("" ::: "memory"); \
                       __builtin_amdgcn_s_barrier(); \
                       asm volatile("" ::: "memory"); } while (0)

__device__ __forceinline__ unsigned short f2bf(float f) {
  union { float f; unsigned int u; } v; v.f = f;
  unsigned int r = v.u + 0x7fffu + ((v.u >> 16) & 1u);  // RNE
  return (unsigned short)(r >> 16);
}

__device__ __forceinline__ unsigned pkbf(float lo, float hi) {
  union { __hip_bfloat162 b; unsigned u; } t;
  t.b = __float22bfloat162_rn(make_float2(lo, hi));   // -> v_cvt_pk_bf16_f32
  return t.u;
}

// ---- mask compaction: idx[b][j] = j-th unmasked key, cnt[b] = count ----------
__global__ void compact_mask(const int* __restrict__ mask,
                             int* __restrict__ idx, int* __restrict__ cnt) {
  const int b = blockIdx.x;
  __shared__ int base, wsum[16];
  if (threadIdx.x == 0) base = 0;
  const int lane = threadIdx.x & 63, w = threadIdx.x >> 6;   // w: 0..15
  __syncthreads();
  for (int c = 0; c < S_; c += 1024) {
    int key = c + threadIdx.x;
    int mv = mask[b * S_ + key];
    unsigned long long bal = __ballot(mv != 0);
    int pre = __popcll(bal & ((1ull << lane) - 1ull));
    if (lane == 0) wsum[w] = __popcll(bal);
    __syncthreads();
    int woff = 0;
#pragma unroll
    for (int i = 0; i < 16; i++) woff += (i < w) ? wsum[i] : 0;
    int tot = 0;
#pragma unroll
    for (int i = 0; i < 16; i++) tot += wsum[i];
    if (mv) idx[b * S_ + base + woff + pre] = key;
    __syncthreads();
    if (threadIdx.x == 0) base += tot;
    __syncthreads();
  }
  if (threadIdx.x == 0) cnt[b] = base;
}

// ---- ALL conversions in ONE launch: query + weights + K/V gather + mem fill --
__global__ void cvt_fused(const float* __restrict__ q,
                          const float* __restrict__ w0, const float* __restrict__ w1,
                          const float* __restrict__ w2, const float* __restrict__ w3,
                          const float* __restrict__ key, const float* __restrict__ value,
                          const float* __restrict__ mk, const float* __restrict__ mv,
                          unsigned short* __restrict__ qf,
                          unsigned short* __restrict__ o0, unsigned short* __restrict__ o1,
                          unsigned short* __restrict__ o2, unsigned short* __restrict__ o3,
                          unsigned short* __restrict__ kf, unsigned short* __restrict__ vf,
                          unsigned short* __restrict__ Kb, unsigned short* __restrict__ Vt,
                          const int* __restrict__ idx, const int* __restrict__ cnt) {
  const size_t NQs = (size_t)B_ * S_ * D_;
  if (blockIdx.x < 8192) {
    size_t i = ((size_t)blockIdx.x * 256 + threadIdx.x) * 4;
    const float* in; unsigned short* out; size_t off;
    if (i < NQs) { in = q; out = qf; off = i; }
    else {
      size_t j = i - NQs;
      int wsel = (int)(j >> 20);
      off = j & ((1u << 20) - 1);
      in  = (wsel == 0) ? w0 : (wsel == 1) ? w1 : (wsel == 2) ? w2 : w3;
      out = (wsel == 0) ? o0 : (wsel == 1) ? o1 : (wsel == 2) ? o2 : o3;
    }
    float4 v = *(const float4*)&in[off];
    ushort4 o;
    o.x = f2bf(v.x); o.y = f2bf(v.y); o.z = f2bf(v.z); o.w = f2bf(v.w);
    *(ushort4*)&out[off] = o;
  } else if (blockIdx.x < 16384) {
    int gid = blockIdx.x - 8192;         // [0, 8192)
    int kv = gid >> 12, rem = gid & 4095;
    int b = rem >> 11, j = rem & 2047;
    if (j >= cnt[b]) return;
    const float* in = kv ? value : key;
    unsigned short* out = kv ? vf : kf;
    int src = idx[b * S_ + j];
    const float* ip = in + ((size_t)(b * S_) + src) * D_;
    unsigned short* op = out + ((size_t)(b * S_) + j) * D_;
    int t = threadIdx.x * 4;
    float4 v = *(const float4*)&ip[t];
    ushort4 o;
    o.x = f2bf(v.x); o.y = f2bf(v.y); o.z = f2bf(v.z); o.w = f2bf(v.w);
    *(ushort4*)&op[t] = o;
  } else {
    // mem fill: 64 blocks x 256 threads x 4 elems = M_*D_ = 65536
    int i = (blockIdx.x - 16384) * 1024 + threadIdx.x * 4;
    int row = i >> 10, col = i & 1023;       // col aligned to 4, same head
    int hI = col >> 6, dd = col & 63;
    float4 a = *(const float4*)&mk[i];
    float4 v = *(const float4*)&mv[i];
    ushort4 ko;
    ko.x = f2bf(8.0f * a.x); ko.y = f2bf(8.0f * a.y);
    ko.z = f2bf(8.0f * a.z); ko.w = f2bf(8.0f * a.w);
    unsigned short vo0 = f2bf(8.0f * v.x), vo1 = f2bf(8.0f * v.y);
    unsigned short vo2 = f2bf(8.0f * v.z), vo3 = f2bf(8.0f * v.w);
#pragma unroll
    for (int b = 0; b < B_; b++) {
      *(ushort4*)&Kb[((size_t)(b * SKM) + S_ + row) * D_ + col] = ko;
      size_t vb = ((size_t)(b * H_ + hI) * HD_ + dd) * SKM + S_ + row;
      Vt[vb] = vo0;
      Vt[vb + SKM] = vo1;
      Vt[vb + 2 * SKM] = vo2;
      Vt[vb + 3 * SKM] = vo3;
    }
  }
}

// ------ gemm_qkv: BK=32 core (best measured 44.6 us tight). -------------------
// 128x128 tile, 8 waves (64x32/wave), 2 buffers, TWO barriers per K-step,
// counted WAITVM(2). LDS 32 KB. Swizzle: LDS[r][c] = global[r][c^((r>>1)&3)].
__global__ __launch_bounds__(512)
void gemm_qkv(const unsigned short* __restrict__ qf, const unsigned short* __restrict__ kf,
              const unsigned short* __restrict__ vf,
              const unsigned short* __restrict__ wq, const unsigned short* __restrict__ wk,
              const unsigned short* __restrict__ wv,
              const float* __restrict__ bq, const float* __restrict__ bk,
              const float* __restrict__ bv,
              unsigned short* __restrict__ Qb, unsigned short* __restrict__ Kb,
              unsigned short* __restrict__ Vt,
              const int* __restrict__ cnt) {
  __shared__ __align__(16) unsigned short As[2 * 128 * 32];
  __shared__ __align__(16) unsigned short Bs[2 * 128 * 32];
  // T1: within each z-slice of 256 works, XCD (bid&7) owns 32 contiguous works
  const int z = blockIdx.x >> 8;
  const int local = blockIdx.x & 255;
  const int wsz = (local & 7) * 32 + (local >> 3);   // bijective (256 = 8*32)
  const int nBase = (wsz & 7) * 128, mBase = (wsz >> 3) * 128;
  const int bb = (mBase >= S_);
  if (z) {   // K/V: skip tiles entirely beyond the compacted row count
    if (mBase - bb * S_ >= cnt[bb]) return;
  }
  const unsigned short* A  = (z == 0) ? qf : (z == 1) ? kf : vf;
  const unsigned short* Bw = (z == 0) ? wq : (z == 1) ? wk : wv;
  const float* bias        = (z == 0) ? bq : (z == 1) ? bk : bv;

  const int tid = threadIdx.x, lane = tid & 63;
  const int w = tid >> 6;                  // 0..7
  const int wr = w >> 2, wc = w & 3;       // 2x4 wave grid, 64x32 per wave
  const int lr = lane & 15, lk = lane >> 4;
  const int srow = tid >> 2;               // staging row 0..127
  const int cd = tid & 3;                  // dest chunk (linear)
  const int ca = cd ^ ((srow >> 1) & 3);   // inverse-swizzled source chunk
  const int NT = D_ / 32;                  // 32

  const f32x4 fz = {0.f, 0.f, 0.f, 0.f};
  f32x4 acc[4][2];
#pragma unroll
  for (int i = 0; i < 4; i++)
#pragma unroll
    for (int j = 0; j < 2; j++) acc[i][j] = fz;

#define STAGE_(buf, k0)                                                          \
  {                                                                              \
    GLOAD16(&A[(size_t)(mBase + srow) * D_ + (k0) + ca * 8],                     \
            &As[(buf) * (128 * 32) + (w * 16) * 32]);                            \
    GLOAD16(&Bw[(size_t)(nBase + srow) * D_ + (k0) + ca * 8],                    \
            &Bs[(buf) * (128 * 32) + (w * 16) * 32]);                            \
  }

  STAGE_(0, 0);                              // 2 loads in flight
  int cur = 0;
  for (int t = 0; t < NT; ++t) {
    if (t + 1 < NT) {
      STAGE_(cur ^ 1, (t + 1) * 32);         // 4 in flight
      WAITVM(2);                             // tile t's 2 done; t+1's in flight
    } else {
      WAITVM(0);
    }
    BARRIER();                               // all waves: tile t staged
    s16x8 af[4], bf[2];
#pragma unroll
    for (int mi = 0; mi < 4; mi++) {
      int row = wr * 64 + mi * 16 + lr;
      af[mi] = *(const s16x8*)&As[cur * (128 * 32) + row * 32 + ((lk ^ ((row >> 1) & 3)) << 3)];
    }
#pragma unroll
    for (int ni = 0; ni < 2; ni++) {
      int row = wc * 32 + ni * 16 + lr;
      bf[ni] = *(const s16x8*)&Bs[cur * (128 * 32) + row * 32 + ((lk ^ ((row >> 1) & 3)) << 3)];
    }
#pragma unroll
    for (int mi = 0; mi < 4; mi++)
#pragma unroll
      for (int ni = 0; ni < 2; ni++)
        acc[mi][ni] = __builtin_amdgcn_mfma_f32_16x16x32_bf16(af[mi], bf[ni], acc[mi][ni], 0, 0, 0);
    BARRIER();   // all waves' reads of buf[cur] latched -> safe to re-stage it
    cur ^= 1;
  }
#undef STAGE_

  const float alpha = (z == 0) ? 0.125f * LOG2E : 1.0f;   // Q: 1/sqrt(HD) * log2(e)
#pragma unroll
  for (int mi = 0; mi < 4; mi++)
#pragma unroll
    for (int ni = 0; ni < 2; ni++)
#pragma unroll
      for (int r = 0; r < 4; r++) {
        int gr = mBase + wr * 64 + mi * 16 + lk * 4 + r;
        int gc = nBase + wc * 32 + ni * 16 + lr;
        float v = (acc[mi][ni][r] + bias[gc]) * alpha;
        if (z == 2) {        // V^T: [b][h][d][key]; keys [0,S_) only
          int s = gr - bb * S_;
          int hI = gc >> 6, dd = gc & 63;
          Vt[((size_t)(bb * H_ + hI) * HD_ + dd) * SKM + s] = f2bf(v);
        } else if (z == 1) { // K rows [0,S_) with per-batch 64-row mem gap
          int orow = gr + bb * M_;
          Kb[(size_t)orow * D_ + gc] = f2bf(v);
        } else {
          Qb[(size_t)gr * D_ + gc] = f2bf(v);
        }
      }
}

// ---- gemm_o: BK=64 core (its best measured). 128x128 tile, 8 waves, ---------
// 2 buffers, two barriers per K-step, counted WAITVM(4). LDS 64 KB.
// Swizzle (8 chunks): LDS[r][c] = global[r][c ^ (r&7)].
__global__ __launch_bounds__(512)
void gemm_o(const unsigned short* __restrict__ A, const unsigned short* __restrict__ Bw,
            const float* __restrict__ bias, float* __restrict__ Cout) {
  __shared__ __align__(16) unsigned short As[2 * 128 * 64];
  __shared__ __align__(16) unsigned short Bs[2 * 128 * 64];
  const int local = blockIdx.x & 255;
  const int wsz = (local & 7) * 32 + (local >> 3);
  const int nBase = (wsz & 7) * 128, mBase = (wsz >> 3) * 128;
  const int tid = threadIdx.x, lane = tid & 63;
  const int w = tid >> 6, wr = w >> 2, wc = w & 3;
  const int lr = lane & 15, lk = lane >> 4;
  const int rg = lane >> 3;                         // row-in-8 (0..7)
  const int sr0 = w * 8 + rg;                       // staging rows sr0, sr0+64
  const int ca = (lane & 7) ^ (rg & 7);             // inverse-swizzled src chunk
  const int NT = D_ / 64;                           // 16

  const f32x4 fz = {0.f, 0.f, 0.f, 0.f};
  f32x4 acc[4][2];
#pragma unroll
  for (int i = 0; i < 4; i++)
#pragma unroll
    for (int j = 0; j < 2; j++) acc[i][j] = fz;

#define STAGE_(buf, k0)                                                          \
  {                                                                              \
    GLOAD16(&A[(size_t)(mBase + sr0) * D_ + (k0) + ca * 8],                      \
            &As[(buf) * (128 * 64) + (w * 8) * 64]);                             \
    GLOAD16(&A[(size_t)(mBase + 64 + sr0) * D_ + (k0) + ca * 8],                 \
            &As[(buf) * (128 * 64) + (64 + w * 8) * 64]);                        \
    GLOAD16(&Bw[(size_t)(nBase + sr0) * D_ + (k0) + ca * 8],                     \
            &Bs[(buf) * (128 * 64) + (w * 8) * 64]);                             \
    GLOAD16(&Bw[(size_t)(nBase + 64 + sr0) * D_ + (k0) + ca * 8],                \
            &Bs[(buf) * (128 * 64) + (64 + w * 8) * 64]);                        \
  }

  STAGE_(0, 0);                              // 4 loads in flight
  int cur = 0;
  for (int t = 0; t < NT; ++t) {
    if (t + 1 < NT) {
      STAGE_(cur ^ 1, (t + 1) * 64);         // 8 in flight
      WAITVM(4);                             // tile t's 4 done; t+1's in flight
    } else {
      WAITVM(0);
    }
    BARRIER();                               // all waves: tile t staged
#pragma unroll
    for (int ks = 0; ks < 2; ks++) {
      s16x8 af[4], bf[2];
#pragma unroll
      for (int mi = 0; mi < 4; mi++) {
        int row = wr * 64 + mi * 16 + lr;
        af[mi] = *(const s16x8*)&As[cur * (128 * 64) + row * 64 + (((ks * 4 + lk) ^ (row & 7)) << 3)];
      }
#pragma unroll
      for (int ni = 0; ni < 2; ni++) {
        int row = wc * 32 + ni * 16 + lr;
        bf[ni] = *(const s16x8*)&Bs[cur * (128 * 64) + row * 64 + (((ks * 4 + lk) ^ (row & 7)) << 3)];
      }
#pragma unroll
      for (int mi = 0; mi < 4; mi++)
#pragma unroll
        for (int ni = 0; ni < 2; ni++)
          acc[mi][ni] = __builtin_amdgcn_mfma_f32_16x16x32_bf16(af[mi], bf[ni], acc[mi][ni], 0, 0, 0);
    }
    BARRIER();   // all waves' reads of buf[cur] latched -> safe to re-stage it
    cur ^= 1;
  }
#undef STAGE_

#pragma unroll
  for (int mi = 0; mi < 4; mi++)
#pragma unroll
    for (int ni = 0; ni < 2; ni++)
#pragma unroll
      for (int r = 0; r < 4; r++) {
        int gr = mBase + wr * 64 + mi * 16 + lk * 4 + r;
        int gc = nBase + wc * 32 + ni * 16 + lr;
        Cout[(size_t)gr * D_ + gc] = acc[mi][ni][r] + bias[gc];
      }
}

// -------- Flash attention: PAIRED 64-key sub-tiles, ONE barrier per 128 keys --
// Tiles: nt_live live-key tiles (tail-masked) + ONE fixed mem tile at key
// offset S_. Block: 256 q-rows (8 waves x 32). Softmax reductions are TREE
// structured (depth 5 vs 16/32 serial chains; nested fmaxf -> v_max3).
__global__ __launch_bounds__(512)
void attn_kernel(const unsigned short* __restrict__ Qb,
                 const unsigned short* __restrict__ Kb,
                 const unsigned short* __restrict__ VtG,
                 const int* __restrict__ cnt,
                 unsigned short* __restrict__ Xb) {
  __shared__ __align__(16) unsigned short Ks[2 * 2 * 64 * 64];   // [buf][sub][key][d]
  __shared__ __align__(16) unsigned short Vs[2 * 2 * 64 * 64];   // [buf][sub][d][key]

  const int tid = threadIdx.x, lane = tid & 63, w = tid >> 6;   // w: 0..7
  const int l31 = lane & 31, hh = lane >> 5;
  const int qt = blockIdx.x, h = blockIdx.y, b = blockIdx.z;

  const int cb = cnt[b];                    // live keys
  const int nt_live = (cb + 63) >> 6;       // live 64-key tiles
  const int ntot = nt_live + 1;             // + fixed mem tile
  const int npair = (ntot + 1) >> 1;

  const int r0 = tid >> 3, c0 = tid & 7;          // staging: row 0..63, chunk 0..7
  const int ck = c0 ^ (r0 & 7);                   // swizzled chunk
  const unsigned short* Kg = Kb + (size_t)b * SKM * D_ + (size_t)h * HD_;
  const unsigned short* Vg = VtG + (size_t)(b * H_ + h) * HD_ * SKM;

  // Q fragments (B-operand of swapped QK^T): Q[q][ds*16 + hh*8 + i]
  const unsigned short* qp = Qb + ((size_t)(b * S_) + qt * 256 + w * 32 + l31) * D_ + h * HD_;
  s16x8 qf[4];
#pragma unroll
  for (int ds = 0; ds < 4; ds++) qf[ds] = *(const s16x8*)&qp[ds * 16 + hh * 8];

  f32x16 accO[2];
#pragma unroll
  for (int dt = 0; dt < 2; dt++)
#pragma unroll
    for (int j = 0; j < 16; j++) accO[dt][j] = 0.f;
  float m_r = -1e20f, l_r = 0.f;

  // key offset of tile t: live tiles at t*64, mem tile at fixed S_
  auto toff = [&](int t) { return (t < nt_live) ? t * 64 : S_; };

  uint4 kr0, kr1, vr0, vr1;
  auto LOAD = [&](int pair) {   // tiles 2p, 2p+1 clamped to ntot-1 (dup unused)
    int t0 = pair * 2;     if (t0 > ntot - 1) t0 = ntot - 1;
    int t1 = pair * 2 + 1; if (t1 > ntot - 1) t1 = ntot - 1;
    int o0 = toff(t0), o1 = toff(t1);
    kr0 = *(const uint4*)&Kg[(size_t)(o0 + r0) * D_ + c0 * 8];
    kr1 = *(const uint4*)&Kg[(size_t)(o1 + r0) * D_ + c0 * 8];
    vr0 = *(const uint4*)&Vg[(size_t)r0 * SKM + o0 + c0 * 8];
    vr1 = *(const uint4*)&Vg[(size_t)r0 * SKM + o1 + c0 * 8];
  };

  LOAD(0);
  *(uint4*)&Ks[r0 * 64 + ck * 8] = kr0;
  *(uint4*)&Ks[4096 + r0 * 64 + ck * 8] = kr1;
  *(uint4*)&Vs[r0 * 64 + ck * 8] = vr0;
  *(uint4*)&Vs[4096 + r0 * 64 + ck * 8] = vr1;
  __syncthreads();
  int cur = 0;

  for (int p = 0; p < npair; ++p) {
    const bool pre = (p + 1 < npair);
    if (pre) LOAD(p + 1);            // issue-early: lands during compute below

#pragma unroll
    for (int s = 0; s < 2; s++) {
      const int kt = p * 2 + s;
      if (kt >= ntot) break;         // uniform (ntot is block-uniform)
      const unsigned short* Kc = &Ks[cur * 8192 + s * 4096];
      const unsigned short* Vc = &Vs[cur * 8192 + s * 4096];

      // ---- S^T = K · Q^T : p0 = keys 0..31, p1 = keys 32..63 (q = l31) ----
      f32x16 p0, p1;
#pragma unroll
      for (int j = 0; j < 16; j++) { p0[j] = 0.f; p1[j] = 0.f; }
      __builtin_amdgcn_s_setprio(1);
#pragma unroll
      for (int ds = 0; ds < 4; ds++) {
        s16x8 ka0 = *(const s16x8*)&Kc[l31 * 64 + (((ds * 2 + hh) ^ (l31 & 7)) << 3)];
        s16x8 ka1 = *(const s16x8*)&Kc[(32 + l31) * 64 + (((ds * 2 + hh) ^ (l31 & 7)) << 3)];
        p0 = __builtin_amdgcn_mfma_f32_32x32x16_bf16(ka0, qf[ds], p0, 0, 0, 0);
        p1 = __builtin_amdgcn_mfma_f32_32x32x16_bf16(ka1, qf[ds], p1, 0, 0, 0);
      }
      __builtin_amdgcn_s_setprio(0);

      // ---- last LIVE tile: kill keys beyond cb (key = (j&3)+8*(j>>2)+4*hh) --
      if (kt == nt_live - 1) {
        int valid = cb - kt * 64;   // 1..64
#pragma unroll
        for (int j = 0; j < 16; j++) {
          int kl = (j & 3) + 8 * (j >> 2) + 4 * hh;
          if (kl >= valid) p0[j] = -1e30f;
          if (kl + 32 >= valid) p1[j] = -1e30f;
        }
      }

      // ---- online softmax in log2 units, defer-max (T13, THR=8) ----
      // tree max: depth 5 instead of 16-deep serial chain (v_max3-friendly)
      float tm[8];
#pragma unroll
      for (int j = 0; j < 8; j++)
        tm[j] = fmaxf(fmaxf(p0[j], p0[j + 8]), fmaxf(p1[j], p1[j + 8]));
#pragma unroll
      for (int off = 4; off >= 1; off >>= 1)
#pragma unroll
        for (int j = 0; j < off; j++) tm[j] = fmaxf(tm[j], tm[j + off]);
      float vmax = fmaxf(tm[0], __shfl_xor(tm[0], 32));
      if (!__all(vmax - m_r <= 8.0f)) {
        float mnew = fmaxf(m_r, vmax);
        float fac = __builtin_amdgcn_exp2f(m_r - mnew);
        m_r = mnew;
        l_r *= fac;
#pragma unroll
        for (int dt = 0; dt < 2; dt++)
#pragma unroll
          for (int j = 0; j < 16; j++) accO[dt][j] *= fac;
      }
      // exp + tree sum (depth 5 instead of 32-deep dependent-add chain)
      float ts[8];
#pragma unroll
      for (int j = 0; j < 16; j++) {
        p0[j] = __builtin_amdgcn_exp2f(p0[j] - m_r);
        p1[j] = __builtin_amdgcn_exp2f(p1[j] - m_r);
      }
#pragma unroll
      for (int j = 0; j < 8; j++)
        ts[j] = (p0[j] + p0[j + 8]) + (p1[j] + p1[j + 8]);
#pragma unroll
      for (int off = 4; off >= 1; off >>= 1)
#pragma unroll
        for (int j = 0; j < off; j++) ts[j] += ts[j + off];
      l_r += ts[0] + __shfl_xor(ts[0], 32);

      // ---- build P^T fragments: frag[ks] = P[q][16ks + hh*8 + 0..7] ----
      s16x8 pf_[4];
#pragma unroll
      for (int ks = 0; ks < 4; ks++) {
        const int base = (ks & 1) * 8;
#define ELT(t) ((ks >= 2) ? p1[base + (t)] : p0[base + (t)])
        unsigned w0 = pkbf(ELT(0), ELT(1));
        unsigned w1 = pkbf(ELT(2), ELT(3));
        unsigned w2 = pkbf(ELT(4), ELT(5));
        unsigned w3 = pkbf(ELT(6), ELT(7));
#undef ELT
        unsigned s0 = hh ? w0 : w2;       // h0 sends keys {8..11}, h1 sends {4..7}
        unsigned s1 = hh ? w1 : w3;
        unsigned g0 = (unsigned)__shfl_xor((int)s0, 32);
        unsigned g1 = (unsigned)__shfl_xor((int)s1, 32);
        union { s16x8 v; unsigned u[4]; } pf;
        pf.u[0] = hh ? g0 : w0;
        pf.u[1] = hh ? g1 : w1;
        pf.u[2] = hh ? w2 : g0;
        pf.u[3] = hh ? w3 : g1;
        pf_[ks] = pf.v;
      }

      // ---- O^T += V^T · P^T  (row d = dt*32+(j&3)+8*(j>>2)+4*hh, q = l31) ---
      __builtin_amdgcn_s_setprio(1);
#pragma unroll
      for (int dt = 0; dt < 2; dt++)
#pragma unroll
        for (int ks = 0; ks < 4; ks++) {
          s16x8 va = *(const s16x8*)&Vc[(dt * 32 + l31) * 64 + (((ks * 2 + hh) ^ (l31 & 7)) << 3)];
          accO[dt] = __builtin_amdgcn_mfma_f32_32x32x16_bf16(va, pf_[ks], accO[dt], 0, 0, 0);
        }
      __builtin_amdgcn_s_setprio(0);
    }

    // ---- write-late: stage pair p+1 into buf^1 (no reader this iter) --------
    if (pre) {
      int ob = (cur ^ 1) * 8192;
      *(uint4*)&Ks[ob + r0 * 64 + ck * 8] = kr0;
      *(uint4*)&Ks[ob + 4096 + r0 * 64 + ck * 8] = kr1;
      *(uint4*)&Vs[ob + r0 * 64 + ck * 8] = vr0;
      *(uint4*)&Vs[ob + 4096 + r0 * 64 + ck * 8] = vr1;
      __syncthreads();               // ONE barrier per 128 keys
      cur ^= 1;
    }
  }

  float invl = 1.0f / l_r;
  size_t orow = ((size_t)(b * S_) + qt * 256 + w * 32 + l31) * D_ + h * HD_;
#pragma unroll
  for (int dt = 0; dt < 2; dt++)
#pragma unroll
    for (int j = 0; j < 16; j++) {
      int d = dt * 32 + (j & 3) + 8 * (j >> 2) + 4 * hh;
      Xb[orow + d] = f2bf(accO[dt][j] * invl);
    }
}

// ------------------------------- launcher -------------------------------------
extern "C" void kernel_launch(void* const* d_in, const int* in_sizes, int n_in,
                              void* d_out, int out_size, void* d_ws, size_t ws_size,
                              hipStream_t stream) {
  const float* query = (const float*)d_in[0];
  const float* key   = (const float*)d_in[1];
  const float* value = (const float*)d_in[2];
  const int*   mask  = (const int*)d_in[3];
  const float* Wq    = (const float*)d_in[4];
  const float* bq    = (const float*)d_in[5];
  const float* Wk    = (const float*)d_in[6];
  const float* bk    = (const float*)d_in[7];
  const float* Wv    = (const float*)d_in[8];
  const float* bv    = (const float*)d_in[9];
  const float* Wo    = (const float*)d_in[10];
  const float* bo    = (const float*)d_in[11];
  const float* m_k   = (const float*)d_in[12];
  const float* m_v   = (const float*)d_in[13];

  const int NQ = B_ * S_ * D_;     // 4,194,304
  const int NW = D_ * D_;          // 1,048,576 = 2^20
  const int NK = B_ * SKM * D_;    // 4,325,376

  unsigned short* ws = (unsigned short*)d_ws;   // ~67.6 MB + 16 KB
  unsigned short* qf = ws;
  unsigned short* kf = qf + NQ;
  unsigned short* vf = kf + NQ;
  unsigned short* wq = vf + NQ;
  unsigned short* wk = wq + NW;
  unsigned short* wv = wk + NW;
  unsigned short* wo = wv + NW;
  unsigned short* Qb = wo + NW;
  unsigned short* Kb = Qb + NQ;
  unsigned short* Vt = Kb + NK;    // [b][h][d][key]
  unsigned short* Xb = Vt + NK;
  int* idx = (int*)(Xb + NQ);      // [B][S]
  int* cnt = idx + B_ * S_;        // [B]

  compact_mask<<<B_, 1024, 0, stream>>>(mask, idx, cnt);
  // one launch: query+weights cvt (8192) + K/V gather (8192) + mem fill (64)
  cvt_fused<<<16448, 256, 0, stream>>>(query, Wq, Wk, Wv, Wo, key, value,
                                       m_k, m_v, qf, wq, wk, wv, wo,
                                       kf, vf, Kb, Vt, idx, cnt);

  // merged Q/K/V projection, BK=32 core (its best measured config)
  gemm_qkv<<<768, 512, 0, stream>>>(qf, kf, vf, wq, wk, wv, bq, bk, bv, Qb, Kb, Vt, cnt);

  attn_kernel<<<dim3(S_ / 256, H_, B_), 512, 0, stream>>>(Qb, Kb, Vt, cnt, Xb);

  // output projection, BK=64 core (its best measured config)
  gemm_o<<<256, 512, 0, stream>>>(Xb, wo, bo, (float*)d_out);
}